// Round 10
// baseline (212.033 us; speedup 1.0000x reference)
//
#include <hip/hip_runtime.h>
#include <math.h>

#define LL 512
#define HH 12
#define DM 384
#define DPAIR 128
#define RK 2176   /* padded K for output GEMM (2112 + 64) */

#define SCALAR_SCALE 0.14433756729740643f   /* (3*16)^-0.5 */
#define POINT_SCALE  0.13608276348795434f   /* (3*4*4.5)^-0.5 */
#define PAIR_SCALE   0.5773502691896258f    /* 3^-0.5 */

typedef short bf16x8 __attribute__((ext_vector_type(8)));
typedef float f32x4 __attribute__((ext_vector_type(4)));

__device__ __forceinline__ float softplusf(float w) {
  return (w > 20.f) ? w : log1pf(expf(w));
}
__device__ __forceinline__ unsigned short f2bf(float f) {
  unsigned int u = __float_as_uint(f);
  u += 0x7fff + ((u >> 16) & 1);   // round-to-nearest-even
  return (unsigned short)(u >> 16);
}

// ---------------- Kernel 1: QKV proj + rotation + extended vectors ----------
// 8 rows per block (halves W L2 re-reads, doubles FMA/load ILP).
__global__ __launch_bounds__(256) void k_qkv(
    const float* __restrict__ x, const float* __restrict__ Ws,
    const float* __restrict__ Wp, const float* __restrict__ rot,
    const float* __restrict__ trans, const float* __restrict__ pwraw,
    unsigned short* __restrict__ qth, unsigned short* __restrict__ kth,
    unsigned short* __restrict__ vsT, unsigned short* __restrict__ vpT)
{
  __shared__ float xs[8][DM];
  __shared__ float rawp[8][576];
  __shared__ float qnl[8][12][4], knl[8][12][4];
  const int l0 = blockIdx.x * 8;
  const int half = blockIdx.y;
  for (int idx = threadIdx.x; idx < 8 * DM; idx += 256)
    xs[idx / DM][idx % DM] = x[(l0 + idx / DM) * DM + idx % DM];
  __syncthreads();
  const float* __restrict__ W = half ? Wp : Ws;
  for (int col = threadIdx.x; col < 576; col += 256) {
    float acc[8] = {0.f, 0.f, 0.f, 0.f, 0.f, 0.f, 0.f, 0.f};
    for (int k4 = 0; k4 < DM / 4; ++k4) {
      const int k = k4 * 4;
      const float w0 = W[(k + 0) * 576 + col];
      const float w1 = W[(k + 1) * 576 + col];
      const float w2 = W[(k + 2) * 576 + col];
      const float w3 = W[(k + 3) * 576 + col];
      #pragma unroll
      for (int r = 0; r < 8; ++r) {
        const float4 xv = *(const float4*)&xs[r][k];
        acc[r] += xv.x * w0 + xv.y * w1 + xv.z * w2 + xv.w * w3;
      }
    }
    if (!half) {
      const int part = col / 192;
      const int h = (col % 192) / 16;
      const int d = col % 16;
      if (part == 0) {
        #pragma unroll
        for (int r = 0; r < 8; ++r)
          qth[(size_t)(h * LL + l0 + r) * 32 + d] = f2bf(SCALAR_SCALE * acc[r]);
      } else if (part == 1) {
        #pragma unroll
        for (int r = 0; r < 8; ++r)
          kth[(size_t)(h * LL + l0 + r) * 32 + d] = f2bf(acc[r]);
      } else {
        #pragma unroll
        for (int r = 0; r < 8; ++r)
          vsT[(size_t)(h * 16 + d) * LL + l0 + r] = f2bf(acc[r]);
      }
    } else {
      #pragma unroll
      for (int r = 0; r < 8; ++r) rawp[r][col] = acc[r];
    }
  }
  if (half) {
    __syncthreads();
    for (int t = threadIdx.x; t < 8 * 192; t += 256) {
      const int r = t / 192, hp = t % 192;
      const int h = hp >> 4, p = hp & 15;
      const int l = l0 + r;
      const float c0 = rawp[r][hp * 3 + 0];
      const float c1 = rawp[r][hp * 3 + 1];
      const float c2 = rawp[r][hp * 3 + 2];
      const float* R = rot + l * 9;
      const float o0 = c0 * R[0] + c1 * R[3] + c2 * R[6] + trans[l * 3 + 0];
      const float o1 = c0 * R[1] + c1 * R[4] + c2 * R[7] + trans[l * 3 + 1];
      const float o2 = c0 * R[2] + c1 * R[5] + c2 * R[8] + trans[l * 3 + 2];
      if (p < 4) {
        const size_t base = (size_t)(h * LL + l) * 32 + 16 + p * 3;
        qth[base + 0] = f2bf(o0);
        qth[base + 1] = f2bf(o1);
        qth[base + 2] = f2bf(o2);
        qnl[r][h][p] = o0 * o0 + o1 * o1 + o2 * o2;
      } else if (p < 8) {
        const float Ch = -0.5f * POINT_SCALE * softplusf(pwraw[h]);
        const size_t base = (size_t)(h * LL + l) * 32 + 16 + (p - 4) * 3;
        kth[base + 0] = f2bf(-2.f * Ch * o0);
        kth[base + 1] = f2bf(-2.f * Ch * o1);
        kth[base + 2] = f2bf(-2.f * Ch * o2);
        knl[r][h][p - 4] = o0 * o0 + o1 * o1 + o2 * o2;
      } else {
        const int pp = p - 8;
        const size_t base = (size_t)(h * 24 + pp * 3) * LL + l;
        vpT[base + 0 * LL] = f2bf(o0);
        vpT[base + 1 * LL] = f2bf(o1);
        vpT[base + 2 * LL] = f2bf(o2);
      }
    }
    __syncthreads();
    if (threadIdx.x < 96) {
      const int r = threadIdx.x / 12, h = threadIdx.x % 12;
      const int l = l0 + r;
      const float qsum = qnl[r][h][0] + qnl[r][h][1] + qnl[r][h][2] + qnl[r][h][3];
      const float ksum = knl[r][h][0] + knl[r][h][1] + knl[r][h][2] + knl[r][h][3];
      const float Ch = -0.5f * POINT_SCALE * softplusf(pwraw[h]);
      const size_t qb = (size_t)(h * LL + l) * 32;
      qth[qb + 28] = f2bf(qsum);
      qth[qb + 29] = f2bf(1.f);
      qth[qb + 30] = 0; qth[qb + 31] = 0;
      kth[qb + 28] = f2bf(Ch);
      kth[qb + 29] = f2bf(Ch * ksum);
      kth[qb + 30] = 0; kth[qb + 31] = 0;
    }
  }
}

// ---------------- Kernel 1b: Wout transpose -> bf16 + zero pads -------------
__global__ __launch_bounds__(256) void k_prep(
    const float* __restrict__ Wout, unsigned short* __restrict__ WoT,
    unsigned short* __restrict__ resultsb)
{
  __shared__ unsigned short t[64][72];
  const int k0 = blockIdx.x * 64;
  const int c0 = blockIdx.y * 64;
  for (int idx = threadIdx.x; idx < 64 * 64; idx += 256) {
    const int r = idx >> 6, c = idx & 63;
    t[c][r] = f2bf(Wout[(size_t)(k0 + r) * 384 + c0 + c]);
  }
  __syncthreads();
  for (int idx = threadIdx.x; idx < 64 * 64; idx += 256) {
    const int n = idx >> 6, k = idx & 63;
    WoT[(size_t)(c0 + n) * RK + k0 + k] = t[n][k];
  }
  if (blockIdx.x == 0) {   // WoT k-pad
    for (int idx = threadIdx.x; idx < 64 * 64; idx += 256) {
      const int n = idx >> 6, k = idx & 63;
      WoT[(size_t)(c0 + n) * RK + 2112 + k] = 0;
    }
  }
  if (blockIdx.y == 0 && blockIdx.x < 8) {   // resultsb col-pad
    const int i0 = blockIdx.x * 64;
    for (int idx = threadIdx.x; idx < 64 * 64; idx += 256) {
      const int r = idx >> 6, c = idx & 63;
      resultsb[(size_t)(i0 + r) * RK + 2112 + c] = 0;
    }
  }
}

// ---------------- Kernel 2: logits via MFMA -> p = exp(l) + Z partials ------
// grid 512 (32 i-tiles x 16 j-tiles of 32), 512 thr. One PR pass (HBM).
// Phase A: two independent MFMA chains per wave for 2x loads in flight.
__global__ __launch_bounds__(512) void k_logits(
    const float* __restrict__ pr, const float* __restrict__ Wpair,
    const float* __restrict__ bpair, const unsigned short* __restrict__ qth,
    const unsigned short* __restrict__ kth, unsigned short* __restrict__ pb,
    float* __restrict__ Zp)
{
  __shared__ float ltile[512 * 13];
  __shared__ __align__(16) unsigned short wTb[16 * 128];
  __shared__ float bpl[12];
  const int tid = threadIdx.x;
  const int wv = tid >> 6, lane = tid & 63;
  const int i0 = (blockIdx.x >> 4) * 16;
  const int jb = blockIdx.x & 15;
  const int j0 = jb * 32;

  for (int t = tid; t < 16 * 128; t += 512) {
    const int h = t >> 7, k = t & 127;
    wTb[t] = (h < HH) ? f2bf(Wpair[k * HH + h]) : (unsigned short)0;
  }
  if (tid < 12) bpl[tid] = bpair[tid];
  __syncthreads();

  bf16x8 bfrag[4];
  {
    const int bh = lane & 15, ch = lane >> 4;
    #pragma unroll
    for (int s = 0; s < 4; ++s)
      bfrag[s] = *(const bf16x8*)&wTb[bh * 128 + s * 32 + ch * 8];
  }

  // pair-bias: A rows = (ii,jj) pairs; two chains (tb, tb+16) per iteration
  for (int tb = wv; tb < 16; tb += 8) {
    const int pi0 = tb * 16 + (lane & 15);
    const int pi1 = (tb + 16) * 16 + (lane & 15);
    const float* arow0 = pr + ((size_t)(i0 + (pi0 >> 5)) * LL + j0 + (pi0 & 31)) * DPAIR
                         + (lane >> 4) * 8;
    const float* arow1 = pr + ((size_t)(i0 + (pi1 >> 5)) * LL + j0 + (pi1 & 31)) * DPAIR
                         + (lane >> 4) * 8;
    f32x4 c0 = (f32x4){0.f, 0.f, 0.f, 0.f};
    f32x4 c1 = (f32x4){0.f, 0.f, 0.f, 0.f};
    #pragma unroll
    for (int s = 0; s < 4; ++s) {
      const float4 u0 = *(const float4*)(arow0 + s * 32);
      const float4 u1 = *(const float4*)(arow0 + s * 32 + 4);
      const float4 v0 = *(const float4*)(arow1 + s * 32);
      const float4 v1 = *(const float4*)(arow1 + s * 32 + 4);
      bf16x8 a0, a1;
      a0[0] = (short)f2bf(u0.x); a0[1] = (short)f2bf(u0.y);
      a0[2] = (short)f2bf(u0.z); a0[3] = (short)f2bf(u0.w);
      a0[4] = (short)f2bf(u1.x); a0[5] = (short)f2bf(u1.y);
      a0[6] = (short)f2bf(u1.z); a0[7] = (short)f2bf(u1.w);
      a1[0] = (short)f2bf(v0.x); a1[1] = (short)f2bf(v0.y);
      a1[2] = (short)f2bf(v0.z); a1[3] = (short)f2bf(v0.w);
      a1[4] = (short)f2bf(v1.x); a1[5] = (short)f2bf(v1.y);
      a1[6] = (short)f2bf(v1.z); a1[7] = (short)f2bf(v1.w);
      c0 = __builtin_amdgcn_mfma_f32_16x16x32_bf16(a0, bfrag[s], c0, 0, 0, 0);
      c1 = __builtin_amdgcn_mfma_f32_16x16x32_bf16(a1, bfrag[s], c1, 0, 0, 0);
    }
    const int hcol = lane & 15;
    if (hcol < HH) {
      #pragma unroll
      for (int q = 0; q < 4; ++q) {
        ltile[(tb * 16 + (lane >> 4) * 4 + q) * 13 + hcol] = c0[q];
        ltile[((tb + 16) * 16 + (lane >> 4) * 4 + q) * 13 + hcol] = c1[q];
      }
    }
  }
  __syncthreads();

  // qk-extended GEMM + assemble + exp -> pb (bf16), p back into ltile
  for (int task = wv; task < 24; task += 8) {
    const int h = task >> 1, jb2 = task & 1;
    const bf16x8 a = *(const bf16x8*)&qth[(size_t)(h * LL + i0 + (lane & 15)) * 32
                                          + (lane >> 4) * 8];
    const bf16x8 b = *(const bf16x8*)&kth[(size_t)(h * LL + j0 + jb2 * 16 + (lane & 15)) * 32
                                          + (lane >> 4) * 8];
    f32x4 c = (f32x4){0.f, 0.f, 0.f, 0.f};
    c = __builtin_amdgcn_mfma_f32_16x16x32_bf16(a, b, c, 0, 0, 0);
    const int j = jb2 * 16 + (lane & 15);
    #pragma unroll
    for (int q = 0; q < 4; ++q) {
      const int ii = (lane >> 4) * 4 + q;
      const float bias = ltile[(ii * 32 + j) * 13 + h];
      const float l = c[q] + PAIR_SCALE * (bias + bpl[h]);
      const float p = __expf(l);
      pb[(size_t)(i0 + ii) * 6144 + h * 512 + j0 + j] = f2bf(p);
      ltile[(ii * 32 + j) * 13 + h] = p;   // same thread re-writes its own slot
    }
  }
  __syncthreads();

  // Z partials: owner thread per (ii,h), deterministic
  if (tid < 192) {
    const int ii = tid / 12, h = tid % 12;
    float s = 0.f;
    for (int j = 0; j < 32; ++j) s += ltile[(ii * 32 + j) * 13 + h];
    Zp[((size_t)jb * LL + i0 + ii) * 12 + h] = s;
  }
}

// ---------------- Kernel 3: res_pair PV, transposed (no LDS transpose) -----
// grid 512 (one block per i), 512 thr (8 waves = 8 d-tiles of 16).
// 2-step k-unroll: both A-fragments' loads issue before the MFMAs.
__global__ __launch_bounds__(512) void k_pv(
    const float* __restrict__ pr, const unsigned short* __restrict__ pb,
    const float* __restrict__ Zp, float* __restrict__ Zi,
    unsigned short* __restrict__ resultsb)
{
  __shared__ __align__(16) unsigned short attn_lds[16 * 544];
  __shared__ float zz[12];
  const int i = blockIdx.x;
  const int tid = threadIdx.x;
  const int wv = tid >> 6, lane = tid & 63;

  // stage p row [12][512] bf16 via uint4; zero rows 12..15
  const uint4* src = (const uint4*)(pb + (size_t)i * 6144);
  for (int t = tid; t < 768; t += 512) {
    const int h = t >> 6, c8 = t & 63;
    *(uint4*)&attn_lds[h * 544 + c8 * 8] = src[t];
  }
  for (int t = tid; t < 272; t += 512)
    *(uint4*)&attn_lds[12 * 544 + t * 8] = (uint4){0, 0, 0, 0};
  if (tid < 12) {
    float s = 0.f;
    #pragma unroll
    for (int jb = 0; jb < 16; ++jb) s += Zp[((size_t)jb * LL + i) * 12 + tid];
    const float r = 1.f / s;
    zz[tid] = r;
    Zi[i * 12 + tid] = r;
  }
  __syncthreads();

  const int d0 = wv * 16;                 // this wave's d-tile
  const int dl = lane & 15;               // A row = d_local
  const int kg = lane >> 4;               // k-group
  const float* __restrict__ base = pr + (size_t)i * (LL * DPAIR) + d0 + dl;

  f32x4 c = (f32x4){0.f, 0.f, 0.f, 0.f};
  for (int ks = 0; ks < 16; ks += 2) {    // k = j, 64 per double-step
    const int j0a = ks * 32 + kg * 8;
    const int j0b = j0a + 32;
    float ra[8], rb[8];
    #pragma unroll
    for (int e = 0; e < 8; ++e) ra[e] = base[(size_t)(j0a + e) * DPAIR];
    #pragma unroll
    for (int e = 0; e < 8; ++e) rb[e] = base[(size_t)(j0b + e) * DPAIR];
    bf16x8 a0, a1;
    #pragma unroll
    for (int e = 0; e < 8; ++e) { a0[e] = (short)f2bf(ra[e]); a1[e] = (short)f2bf(rb[e]); }
    const bf16x8 b0 = *(const bf16x8*)&attn_lds[(lane & 15) * 544 + ks * 32 + kg * 8];
    const bf16x8 b1 = *(const bf16x8*)&attn_lds[(lane & 15) * 544 + (ks + 1) * 32 + kg * 8];
    c = __builtin_amdgcn_mfma_f32_16x16x32_bf16(a0, b0, c, 0, 0, 0);
    c = __builtin_amdgcn_mfma_f32_16x16x32_bf16(a1, b1, c, 0, 0, 0);
  }
  // D: col = lane&15 = h, row = (lane>>4)*4+q = d_local
  const int h = lane & 15;
  if (h < HH) {
    const float zv = zz[h];
    #pragma unroll
    for (int q = 0; q < 4; ++q) {
      const int d = d0 + (lane >> 4) * 4 + q;
      resultsb[(size_t)i * RK + 576 + h * 128 + d] = f2bf(c[q] * zv);
    }
  }
}

// ---------------- Kernel 4: res_s / res_p via Q-tiled MFMA ------------------
// grid (36 col-blocks, 8 i-tiles), 256 thr (4 waves = 4 M-tiles of 16 i).
__global__ __launch_bounds__(256) void k_sv(
    const unsigned short* __restrict__ pb, const unsigned short* __restrict__ vsT,
    const unsigned short* __restrict__ vpT, const float* __restrict__ Zi,
    const float* __restrict__ rot, const float* __restrict__ trans,
    unsigned short* __restrict__ resultsb)
{
  __shared__ float cl[4][16][16];
  const int cb = blockIdx.x;
  const int it = blockIdx.y;
  const int tid = threadIdx.x;
  const int wvv = tid >> 6, lane = tid & 63;
  int h, rowbase, isvp = 0, halfb = 0;
  if (cb < 12) { h = cb; rowbase = h * 16; }
  else { const int v = cb - 12; h = v >> 1; halfb = v & 1; isvp = 1;
         rowbase = h * 24 + halfb * 8; }
  const unsigned short* __restrict__ vT = isvp ? vpT : vsT;
  const int ibase = it * 64 + wvv * 16;

  f32x4 c = (f32x4){0.f, 0.f, 0.f, 0.f};
  for (int ks = 0; ks < 16; ++ks) {
    const bf16x8 a = *(const bf16x8*)&pb[(size_t)(ibase + (lane & 15)) * 6144
                                         + h * 512 + ks * 32 + (lane >> 4) * 8];
    const bf16x8 b = *(const bf16x8*)&vT[(size_t)(rowbase + (lane & 15)) * LL
                                         + ks * 32 + (lane >> 4) * 8];
    c = __builtin_amdgcn_mfma_f32_16x16x32_bf16(a, b, c, 0, 0, 0);
  }
  if (!isvp) {
    #pragma unroll
    for (int r = 0; r < 4; ++r) {
      const int ii = ibase + (lane >> 4) * 4 + r;
      resultsb[(size_t)ii * RK + h * 16 + (lane & 15)] =
          f2bf(c[r] * Zi[ii * 12 + h]);
    }
  } else {
    #pragma unroll
    for (int r = 0; r < 4; ++r) {
      const int ii = ibase + (lane >> 4) * 4 + r;
      cl[wvv][(lane >> 4) * 4 + r][lane & 15] = c[r] * Zi[ii * 12 + h];
    }
    __syncthreads();
    const int np = halfb ? 3 : 5;
    for (int t = tid; t < 64 * np; t += 256) {
      const int il = t / np, pl = t % np;
      const int p = halfb ? 5 + pl : pl;
      const int lc = p * 3 - (halfb ? 8 : 0);
      const int ii = it * 64 + il;
      const float a0 = cl[il >> 4][il & 15][lc + 0] - trans[ii * 3 + 0];
      const float a1 = cl[il >> 4][il & 15][lc + 1] - trans[ii * 3 + 1];
      const float a2 = cl[il >> 4][il & 15][lc + 2] - trans[ii * 3 + 2];
      const float* R = rot + ii * 9;
      const float o0 = a0 * R[0] + a1 * R[1] + a2 * R[2];
      const float o1 = a0 * R[3] + a1 * R[4] + a2 * R[5];
      const float o2 = a0 * R[6] + a1 * R[7] + a2 * R[8];
      unsigned short* rr = resultsb + (size_t)ii * RK;
      rr[192 + h * 24 + p * 3 + 0] = f2bf(o0);
      rr[192 + h * 24 + p * 3 + 1] = f2bf(o1);
      rr[192 + h * 24 + p * 3 + 2] = f2bf(o2);
      rr[480 + h * 8 + p] = f2bf(sqrtf(o0 * o0 + o1 * o1 + o2 * o2 + 1e-8f));
    }
  }
}

// ---------------- Kernel 5a: output GEMM via MFMA, K-split ------------------
__global__ __launch_bounds__(256) void k_outg(
    const unsigned short* __restrict__ resb, const unsigned short* __restrict__ WoT,
    float* __restrict__ partial)
{
  const int i0 = blockIdx.x * 64;
  const int c0 = blockIdx.y * 64;
  const int k0 = blockIdx.z * 544;
  const int wv = threadIdx.x >> 6, lane = threadIdx.x & 63;
  const int aRow = i0 + wv * 16 + (lane & 15);

  f32x4 acc0 = (f32x4){0.f, 0.f, 0.f, 0.f};
  f32x4 acc1 = (f32x4){0.f, 0.f, 0.f, 0.f};
  f32x4 acc2 = (f32x4){0.f, 0.f, 0.f, 0.f};
  f32x4 acc3 = (f32x4){0.f, 0.f, 0.f, 0.f};
  for (int ks = 0; ks < 17; ++ks) {
    const int kk = k0 + ks * 32 + (lane >> 4) * 8;
    const bf16x8 a = *(const bf16x8*)&resb[(size_t)aRow * RK + kk];
    const bf16x8 b0 = *(const bf16x8*)&WoT[(size_t)(c0 + 0 * 16 + (lane & 15)) * RK + kk];
    const bf16x8 b1 = *(const bf16x8*)&WoT[(size_t)(c0 + 1 * 16 + (lane & 15)) * RK + kk];
    const bf16x8 b2 = *(const bf16x8*)&WoT[(size_t)(c0 + 2 * 16 + (lane & 15)) * RK + kk];
    const bf16x8 b3 = *(const bf16x8*)&WoT[(size_t)(c0 + 3 * 16 + (lane & 15)) * RK + kk];
    acc0 = __builtin_amdgcn_mfma_f32_16x16x32_bf16(a, b0, acc0, 0, 0, 0);
    acc1 = __builtin_amdgcn_mfma_f32_16x16x32_bf16(a, b1, acc1, 0, 0, 0);
    acc2 = __builtin_amdgcn_mfma_f32_16x16x32_bf16(a, b2, acc2, 0, 0, 0);
    acc3 = __builtin_amdgcn_mfma_f32_16x16x32_bf16(a, b3, acc3, 0, 0, 0);
  }
  float* pbase = partial + (size_t)blockIdx.z * (LL * 384);
  #pragma unroll
  for (int r = 0; r < 4; ++r) {
    const int ii = i0 + wv * 16 + (lane >> 4) * 4 + r;
    float* prow = pbase + (size_t)ii * 384 + c0 + (lane & 15);
    prow[0]  = acc0[r];
    prow[16] = acc1[r];
    prow[32] = acc2[r];
    prow[48] = acc3[r];
  }
}

// ---------------- Kernel 5b: reduce partials + bias -------------------------
__global__ __launch_bounds__(256) void k_out2(
    const float* __restrict__ partial, const float* __restrict__ bout,
    float* __restrict__ out)
{
  const int e = blockIdx.x * 256 + threadIdx.x;
  const int c = e % 384;
  out[e] = bout[c] + partial[e] + partial[e + LL * 384]
         + partial[e + 2 * LL * 384] + partial[e + 3 * LL * 384];
}

extern "C" void kernel_launch(void* const* d_in, const int* in_sizes, int n_in,
                              void* d_out, int out_size, void* d_ws, size_t ws_size,
                              hipStream_t stream)
{
  const float* x     = (const float*)d_in[0];
  const float* prw   = (const float*)d_in[1];
  const float* rot   = (const float*)d_in[2];
  const float* trans = (const float*)d_in[3];
  const float* Ws    = (const float*)d_in[4];
  const float* Wp    = (const float*)d_in[5];
  const float* pw    = (const float*)d_in[6];
  const float* Wpair = (const float*)d_in[7];
  const float* bpair = (const float*)d_in[8];
  const float* Wout  = (const float*)d_in[9];
  const float* bout  = (const float*)d_in[10];

  float* ws = (float*)d_ws;
  unsigned short* qth = (unsigned short*)ws;                // 98304 f
  unsigned short* kth = (unsigned short*)(ws + 98304);      // 98304 f
  unsigned short* vsT = (unsigned short*)(ws + 196608);     // 49152 f
  unsigned short* vpT = (unsigned short*)(ws + 245760);     // 73728 f
  unsigned short* pb  = (unsigned short*)(ws + 319488);     // 1572864 f
  float* Zp      = ws + 1892352;                            // 16*512*12 = 98304 f
  float* Zi      = ws + 1990656;                            // 6144 f
  unsigned short* resultsb = (unsigned short*)(ws + 1996800); // 557056 f
  unsigned short* WoT = (unsigned short*)(ws + 2553856);    // 417792 f
  float* partial = ws + 2971648;                            // 786432 f
  float* out     = (float*)d_out;

  k_qkv<<<dim3(64, 2), 256, 0, stream>>>(x, Ws, Wp, rot, trans, pw,
                                         qth, kth, vsT, vpT);
  k_prep<<<dim3(33, 6), 256, 0, stream>>>(Wout, WoT, resultsb);
  k_logits<<<512, 512, 0, stream>>>(prw, Wpair, bpair, qth, kth, pb, Zp);
  k_pv<<<512, 512, 0, stream>>>(prw, pb, Zp, Zi, resultsb);
  k_sv<<<dim3(36, 8), 256, 0, stream>>>(pb, vsT, vpT, Zi, rot, trans, resultsb);
  k_outg<<<dim3(8, 6, 4), 256, 0, stream>>>(resultsb, WoT, partial);
  k_out2<<<768, 256, 0, stream>>>(partial, bout, out);
}

// Round 11
// 108.881 us; speedup vs baseline: 1.9474x; 1.9474x over previous
//
#include <hip/hip_runtime.h>
#include <math.h>

#define LL 512
#define HH 12
#define DM 384
#define DPAIR 128
#define RK 2176   /* padded K for output GEMM (2112 + 64) */

#define SCALAR_SCALE 0.14433756729740643f   /* (3*16)^-0.5 */
#define POINT_SCALE  0.13608276348795434f   /* (3*4*4.5)^-0.5 */
#define PAIR_SCALE   0.5773502691896258f    /* 3^-0.5 */

typedef short bf16x8 __attribute__((ext_vector_type(8)));
typedef float f32x4 __attribute__((ext_vector_type(4)));

__device__ __forceinline__ float softplusf(float w) {
  return (w > 20.f) ? w : log1pf(expf(w));
}
__device__ __forceinline__ unsigned short f2bf(float f) {
  unsigned int u = __float_as_uint(f);
  u += 0x7fff + ((u >> 16) & 1);   // round-to-nearest-even
  return (unsigned short)(u >> 16);
}

// ---------------- Kernel 0a: x -> bf16 ---------------------------------------
__global__ __launch_bounds__(256) void k_prepx(
    const float* __restrict__ x, unsigned short* __restrict__ xb)
{
  const int t = blockIdx.x * 256 + threadIdx.x;   // 24576 threads, 8 elems each
  const float4 v0 = ((const float4*)x)[t * 2];
  const float4 v1 = ((const float4*)x)[t * 2 + 1];
  unsigned int w[4];
  w[0] = (unsigned)f2bf(v0.x) | ((unsigned)f2bf(v0.y) << 16);
  w[1] = (unsigned)f2bf(v0.z) | ((unsigned)f2bf(v0.w) << 16);
  w[2] = (unsigned)f2bf(v1.x) | ((unsigned)f2bf(v1.y) << 16);
  w[3] = (unsigned)f2bf(v1.z) | ((unsigned)f2bf(v1.w) << 16);
  *(uint4*)&xb[t * 8] = *(uint4*)w;
}

// ---------------- Kernel 0b: Ws|Wp -> WcatT bf16 [1152][384] -----------------
__global__ __launch_bounds__(256) void k_prepw(
    const float* __restrict__ Ws, const float* __restrict__ Wp,
    unsigned short* __restrict__ WcatT)
{
  __shared__ unsigned short t[64][72];
  const int c0 = blockIdx.x * 64;                 // 18 tiles -> 1152
  const int k0 = blockIdx.y * 64;                 // 6 tiles -> 384
  const float* __restrict__ W = (c0 < 576) ? Ws : Wp;
  const int cb = (c0 < 576) ? c0 : c0 - 576;
  for (int idx = threadIdx.x; idx < 64 * 64; idx += 256) {
    const int r = idx >> 6, c = idx & 63;
    t[c][r] = f2bf(W[(size_t)(k0 + r) * 576 + cb + c]);
  }
  __syncthreads();
  for (int idx = threadIdx.x; idx < 64 * 64; idx += 256) {
    const int n = idx >> 6, k = idx & 63;
    WcatT[(size_t)(c0 + n) * 384 + k0 + k] = t[n][k];
  }
}

// ---------------- Kernel 1: QKV projection via MFMA --------------------------
// grid (8 i-tiles of 64, 72 c-tiles of 16), 256 thr (4 waves = 4 i-subtiles).
__global__ __launch_bounds__(256) void k_qkv_gemm(
    const unsigned short* __restrict__ xb, const unsigned short* __restrict__ WcatT,
    float* __restrict__ rawq)
{
  const int i0 = blockIdx.x * 64;
  const int c0 = blockIdx.y * 16;
  const int wv = threadIdx.x >> 6, lane = threadIdx.x & 63;
  const int aRow = i0 + wv * 16 + (lane & 15);
  const int kg = lane >> 4;

  f32x4 acc = (f32x4){0.f, 0.f, 0.f, 0.f};
  const unsigned short* arow = xb + (size_t)aRow * DM + kg * 8;
  const unsigned short* brow = WcatT + (size_t)(c0 + (lane & 15)) * DM + kg * 8;
  #pragma unroll
  for (int ks = 0; ks < 12; ks += 2) {
    const bf16x8 a0 = *(const bf16x8*)(arow + ks * 32);
    const bf16x8 b0 = *(const bf16x8*)(brow + ks * 32);
    const bf16x8 a1 = *(const bf16x8*)(arow + (ks + 1) * 32);
    const bf16x8 b1 = *(const bf16x8*)(brow + (ks + 1) * 32);
    acc = __builtin_amdgcn_mfma_f32_16x16x32_bf16(a0, b0, acc, 0, 0, 0);
    acc = __builtin_amdgcn_mfma_f32_16x16x32_bf16(a1, b1, acc, 0, 0, 0);
  }
  #pragma unroll
  for (int q = 0; q < 4; ++q) {
    const int ii = i0 + wv * 16 + (lane >> 4) * 4 + q;
    rawq[(size_t)ii * 1152 + c0 + (lane & 15)] = acc[q];
  }
}

// ---------------- Kernel 1c: rotation/translation + extended vectors --------
// grid 128 (4 rows each), 256 thr. Reads rawq, writes qth/kth/vsT/vpT.
__global__ __launch_bounds__(256) void k_post(
    const float* __restrict__ rawq, const float* __restrict__ rot,
    const float* __restrict__ trans, const float* __restrict__ pwraw,
    unsigned short* __restrict__ qth, unsigned short* __restrict__ kth,
    unsigned short* __restrict__ vsT, unsigned short* __restrict__ vpT)
{
  __shared__ float qnl[4][12][4], knl[4][12][4];
  const int l0 = blockIdx.x * 4;

  // scalar half: cols 0..575
  for (int t = threadIdx.x; t < 4 * 576; t += 256) {
    const int r = t / 576, col = t % 576;
    const float v = rawq[(size_t)(l0 + r) * 1152 + col];
    const int part = col / 192;
    const int h = (col % 192) / 16;
    const int d = col % 16;
    if (part == 0)
      qth[(size_t)(h * LL + l0 + r) * 32 + d] = f2bf(SCALAR_SCALE * v);
    else if (part == 1)
      kth[(size_t)(h * LL + l0 + r) * 32 + d] = f2bf(v);
    else
      vsT[(size_t)(h * 16 + d) * LL + l0 + r] = f2bf(v);
  }
  // point half: cols 576..1151 (hp*3 + axis, hp = h*16+p)
  for (int t = threadIdx.x; t < 4 * 192; t += 256) {
    const int r = t / 192, hp = t % 192;
    const int h = hp >> 4, p = hp & 15;
    const int l = l0 + r;
    const float* rr = rawq + (size_t)l * 1152 + 576 + hp * 3;
    const float c0 = rr[0], c1 = rr[1], c2 = rr[2];
    const float* R = rot + l * 9;
    const float o0 = c0 * R[0] + c1 * R[3] + c2 * R[6] + trans[l * 3 + 0];
    const float o1 = c0 * R[1] + c1 * R[4] + c2 * R[7] + trans[l * 3 + 1];
    const float o2 = c0 * R[2] + c1 * R[5] + c2 * R[8] + trans[l * 3 + 2];
    if (p < 4) {
      const size_t base = (size_t)(h * LL + l) * 32 + 16 + p * 3;
      qth[base + 0] = f2bf(o0);
      qth[base + 1] = f2bf(o1);
      qth[base + 2] = f2bf(o2);
      qnl[r][h][p] = o0 * o0 + o1 * o1 + o2 * o2;
    } else if (p < 8) {
      const float Ch = -0.5f * POINT_SCALE * softplusf(pwraw[h]);
      const size_t base = (size_t)(h * LL + l) * 32 + 16 + (p - 4) * 3;
      kth[base + 0] = f2bf(-2.f * Ch * o0);
      kth[base + 1] = f2bf(-2.f * Ch * o1);
      kth[base + 2] = f2bf(-2.f * Ch * o2);
      knl[r][h][p - 4] = o0 * o0 + o1 * o1 + o2 * o2;
    } else {
      const int pp = p - 8;
      const size_t base = (size_t)(h * 24 + pp * 3) * LL + l;
      vpT[base + 0 * LL] = f2bf(o0);
      vpT[base + 1 * LL] = f2bf(o1);
      vpT[base + 2 * LL] = f2bf(o2);
    }
  }
  __syncthreads();
  if (threadIdx.x < 48) {
    const int r = threadIdx.x / 12, h = threadIdx.x % 12;
    const int l = l0 + r;
    const float qsum = qnl[r][h][0] + qnl[r][h][1] + qnl[r][h][2] + qnl[r][h][3];
    const float ksum = knl[r][h][0] + knl[r][h][1] + knl[r][h][2] + knl[r][h][3];
    const float Ch = -0.5f * POINT_SCALE * softplusf(pwraw[h]);
    const size_t qb = (size_t)(h * LL + l) * 32;
    qth[qb + 28] = f2bf(qsum);
    qth[qb + 29] = f2bf(1.f);
    qth[qb + 30] = 0; qth[qb + 31] = 0;
    kth[qb + 28] = f2bf(Ch);
    kth[qb + 29] = f2bf(Ch * ksum);
    kth[qb + 30] = 0; kth[qb + 31] = 0;
  }
}

// ---------------- Kernel 1b: Wout transpose -> bf16 + zero pads -------------
__global__ __launch_bounds__(256) void k_prep(
    const float* __restrict__ Wout, unsigned short* __restrict__ WoT,
    unsigned short* __restrict__ resultsb)
{
  __shared__ unsigned short t[64][72];
  const int k0 = blockIdx.x * 64;
  const int c0 = blockIdx.y * 64;
  for (int idx = threadIdx.x; idx < 64 * 64; idx += 256) {
    const int r = idx >> 6, c = idx & 63;
    t[c][r] = f2bf(Wout[(size_t)(k0 + r) * 384 + c0 + c]);
  }
  __syncthreads();
  for (int idx = threadIdx.x; idx < 64 * 64; idx += 256) {
    const int n = idx >> 6, k = idx & 63;
    WoT[(size_t)(c0 + n) * RK + k0 + k] = t[n][k];
  }
  if (blockIdx.x == 0) {   // WoT k-pad
    for (int idx = threadIdx.x; idx < 64 * 64; idx += 256) {
      const int n = idx >> 6, k = idx & 63;
      WoT[(size_t)(c0 + n) * RK + 2112 + k] = 0;
    }
  }
  if (blockIdx.y == 0 && blockIdx.x < 8) {   // resultsb col-pad
    const int i0 = blockIdx.x * 64;
    for (int idx = threadIdx.x; idx < 64 * 64; idx += 256) {
      const int r = idx >> 6, c = idx & 63;
      resultsb[(size_t)(i0 + r) * RK + 2112 + c] = 0;
    }
  }
}

// ---------------- Kernel 2: logits via MFMA -> p = exp(l) + Z partials ------
// grid 512 (32 i-tiles x 16 j-tiles of 32), 512 thr. One PR pass (HBM).
__global__ __launch_bounds__(512) void k_logits(
    const float* __restrict__ pr, const float* __restrict__ Wpair,
    const float* __restrict__ bpair, const unsigned short* __restrict__ qth,
    const unsigned short* __restrict__ kth, unsigned short* __restrict__ pb,
    float* __restrict__ Zp)
{
  __shared__ float ltile[512 * 13];
  __shared__ __align__(16) unsigned short wTb[16 * 128];
  __shared__ float bpl[12];
  const int tid = threadIdx.x;
  const int wv = tid >> 6, lane = tid & 63;
  const int i0 = (blockIdx.x >> 4) * 16;
  const int jb = blockIdx.x & 15;
  const int j0 = jb * 32;

  for (int t = tid; t < 16 * 128; t += 512) {
    const int h = t >> 7, k = t & 127;
    wTb[t] = (h < HH) ? f2bf(Wpair[k * HH + h]) : (unsigned short)0;
  }
  if (tid < 12) bpl[tid] = bpair[tid];
  __syncthreads();

  bf16x8 bfrag[4];
  {
    const int bh = lane & 15, ch = lane >> 4;
    #pragma unroll
    for (int s = 0; s < 4; ++s)
      bfrag[s] = *(const bf16x8*)&wTb[bh * 128 + s * 32 + ch * 8];
  }

  // pair-bias: A rows = (ii,jj) pairs; two chains (tb, tb+16) per iteration
  for (int tb = wv; tb < 16; tb += 8) {
    const int pi0 = tb * 16 + (lane & 15);
    const int pi1 = (tb + 16) * 16 + (lane & 15);
    const float* arow0 = pr + ((size_t)(i0 + (pi0 >> 5)) * LL + j0 + (pi0 & 31)) * DPAIR
                         + (lane >> 4) * 8;
    const float* arow1 = pr + ((size_t)(i0 + (pi1 >> 5)) * LL + j0 + (pi1 & 31)) * DPAIR
                         + (lane >> 4) * 8;
    f32x4 c0 = (f32x4){0.f, 0.f, 0.f, 0.f};
    f32x4 c1 = (f32x4){0.f, 0.f, 0.f, 0.f};
    #pragma unroll
    for (int s = 0; s < 4; ++s) {
      const float4 u0 = *(const float4*)(arow0 + s * 32);
      const float4 u1 = *(const float4*)(arow0 + s * 32 + 4);
      const float4 v0 = *(const float4*)(arow1 + s * 32);
      const float4 v1 = *(const float4*)(arow1 + s * 32 + 4);
      bf16x8 a0, a1;
      a0[0] = (short)f2bf(u0.x); a0[1] = (short)f2bf(u0.y);
      a0[2] = (short)f2bf(u0.z); a0[3] = (short)f2bf(u0.w);
      a0[4] = (short)f2bf(u1.x); a0[5] = (short)f2bf(u1.y);
      a0[6] = (short)f2bf(u1.z); a0[7] = (short)f2bf(u1.w);
      a1[0] = (short)f2bf(v0.x); a1[1] = (short)f2bf(v0.y);
      a1[2] = (short)f2bf(v0.z); a1[3] = (short)f2bf(v0.w);
      a1[4] = (short)f2bf(v1.x); a1[5] = (short)f2bf(v1.y);
      a1[6] = (short)f2bf(v1.z); a1[7] = (short)f2bf(v1.w);
      c0 = __builtin_amdgcn_mfma_f32_16x16x32_bf16(a0, bfrag[s], c0, 0, 0, 0);
      c1 = __builtin_amdgcn_mfma_f32_16x16x32_bf16(a1, bfrag[s], c1, 0, 0, 0);
    }
    const int hcol = lane & 15;
    if (hcol < HH) {
      #pragma unroll
      for (int q = 0; q < 4; ++q) {
        ltile[(tb * 16 + (lane >> 4) * 4 + q) * 13 + hcol] = c0[q];
        ltile[((tb + 16) * 16 + (lane >> 4) * 4 + q) * 13 + hcol] = c1[q];
      }
    }
  }
  __syncthreads();

  // qk-extended GEMM + assemble + exp -> pb (bf16), p back into ltile
  for (int task = wv; task < 24; task += 8) {
    const int h = task >> 1, jb2 = task & 1;
    const bf16x8 a = *(const bf16x8*)&qth[(size_t)(h * LL + i0 + (lane & 15)) * 32
                                          + (lane >> 4) * 8];
    const bf16x8 b = *(const bf16x8*)&kth[(size_t)(h * LL + j0 + jb2 * 16 + (lane & 15)) * 32
                                          + (lane >> 4) * 8];
    f32x4 c = (f32x4){0.f, 0.f, 0.f, 0.f};
    c = __builtin_amdgcn_mfma_f32_16x16x32_bf16(a, b, c, 0, 0, 0);
    const int j = jb2 * 16 + (lane & 15);
    #pragma unroll
    for (int q = 0; q < 4; ++q) {
      const int ii = (lane >> 4) * 4 + q;
      const float bias = ltile[(ii * 32 + j) * 13 + h];
      const float l = c[q] + PAIR_SCALE * (bias + bpl[h]);
      const float p = __expf(l);
      pb[(size_t)(i0 + ii) * 6144 + h * 512 + j0 + j] = f2bf(p);
      ltile[(ii * 32 + j) * 13 + h] = p;   // same thread re-writes its own slot
    }
  }
  __syncthreads();

  // Z partials: owner thread per (ii,h), deterministic
  if (tid < 192) {
    const int ii = tid / 12, h = tid % 12;
    float s = 0.f;
    for (int j = 0; j < 32; ++j) s += ltile[(ii * 32 + j) * 13 + h];
    Zp[((size_t)jb * LL + i0 + ii) * 12 + h] = s;
  }
}

// ---------------- Kernel 3: res_pair PV, transposed (no LDS transpose) -----
// grid 512 (one block per i), 512 thr (8 waves = 8 d-tiles of 16).
__global__ __launch_bounds__(512) void k_pv(
    const float* __restrict__ pr, const unsigned short* __restrict__ pb,
    const float* __restrict__ Zp, float* __restrict__ Zi,
    unsigned short* __restrict__ resultsb)
{
  __shared__ __align__(16) unsigned short attn_lds[16 * 544];
  __shared__ float zz[12];
  const int i = blockIdx.x;
  const int tid = threadIdx.x;
  const int wv = tid >> 6, lane = tid & 63;

  // stage p row [12][512] bf16 via uint4; zero rows 12..15
  const uint4* src = (const uint4*)(pb + (size_t)i * 6144);
  for (int t = tid; t < 768; t += 512) {
    const int h = t >> 6, c8 = t & 63;
    *(uint4*)&attn_lds[h * 544 + c8 * 8] = src[t];
  }
  for (int t = tid; t < 272; t += 512)
    *(uint4*)&attn_lds[12 * 544 + t * 8] = (uint4){0, 0, 0, 0};
  if (tid < 12) {
    float s = 0.f;
    #pragma unroll
    for (int jb = 0; jb < 16; ++jb) s += Zp[((size_t)jb * LL + i) * 12 + tid];
    const float r = 1.f / s;
    zz[tid] = r;
    Zi[i * 12 + tid] = r;
  }
  __syncthreads();

  const int d0 = wv * 16;                 // this wave's d-tile
  const int dl = lane & 15;               // A row = d_local
  const int kg = lane >> 4;               // k-group
  const float* __restrict__ base = pr + (size_t)i * (LL * DPAIR) + d0 + dl;

  f32x4 c = (f32x4){0.f, 0.f, 0.f, 0.f};
  for (int ks = 0; ks < 16; ks += 2) {    // k = j, 64 per double-step
    const int j0a = ks * 32 + kg * 8;
    const int j0b = j0a + 32;
    float ra[8], rb[8];
    #pragma unroll
    for (int e = 0; e < 8; ++e) ra[e] = base[(size_t)(j0a + e) * DPAIR];
    #pragma unroll
    for (int e = 0; e < 8; ++e) rb[e] = base[(size_t)(j0b + e) * DPAIR];
    bf16x8 a0, a1;
    #pragma unroll
    for (int e = 0; e < 8; ++e) { a0[e] = (short)f2bf(ra[e]); a1[e] = (short)f2bf(rb[e]); }
    const bf16x8 b0 = *(const bf16x8*)&attn_lds[(lane & 15) * 544 + ks * 32 + kg * 8];
    const bf16x8 b1 = *(const bf16x8*)&attn_lds[(lane & 15) * 544 + (ks + 1) * 32 + kg * 8];
    c = __builtin_amdgcn_mfma_f32_16x16x32_bf16(a0, b0, c, 0, 0, 0);
    c = __builtin_amdgcn_mfma_f32_16x16x32_bf16(a1, b1, c, 0, 0, 0);
  }
  // D: col = lane&15 = h, row = (lane>>4)*4+q = d_local
  const int h = lane & 15;
  if (h < HH) {
    const float zv = zz[h];
    #pragma unroll
    for (int q = 0; q < 4; ++q) {
      const int d = d0 + (lane >> 4) * 4 + q;
      resultsb[(size_t)i * RK + 576 + h * 128 + d] = f2bf(c[q] * zv);
    }
  }
}

// ---------------- Kernel 4: res_s / res_p via Q-tiled MFMA ------------------
// grid (36 col-blocks, 8 i-tiles), 256 thr (4 waves = 4 M-tiles of 16 i).
__global__ __launch_bounds__(256) void k_sv(
    const unsigned short* __restrict__ pb, const unsigned short* __restrict__ vsT,
    const unsigned short* __restrict__ vpT, const float* __restrict__ Zi,
    const float* __restrict__ rot, const float* __restrict__ trans,
    unsigned short* __restrict__ resultsb)
{
  __shared__ float cl[4][16][16];
  const int cb = blockIdx.x;
  const int it = blockIdx.y;
  const int tid = threadIdx.x;
  const int wvv = tid >> 6, lane = tid & 63;
  int h, rowbase, isvp = 0, halfb = 0;
  if (cb < 12) { h = cb; rowbase = h * 16; }
  else { const int v = cb - 12; h = v >> 1; halfb = v & 1; isvp = 1;
         rowbase = h * 24 + halfb * 8; }
  const unsigned short* __restrict__ vT = isvp ? vpT : vsT;
  const int ibase = it * 64 + wvv * 16;

  f32x4 c = (f32x4){0.f, 0.f, 0.f, 0.f};
  for (int ks = 0; ks < 16; ++ks) {
    const bf16x8 a = *(const bf16x8*)&pb[(size_t)(ibase + (lane & 15)) * 6144
                                         + h * 512 + ks * 32 + (lane >> 4) * 8];
    const bf16x8 b = *(const bf16x8*)&vT[(size_t)(rowbase + (lane & 15)) * LL
                                         + ks * 32 + (lane >> 4) * 8];
    c = __builtin_amdgcn_mfma_f32_16x16x32_bf16(a, b, c, 0, 0, 0);
  }
  if (!isvp) {
    #pragma unroll
    for (int r = 0; r < 4; ++r) {
      const int ii = ibase + (lane >> 4) * 4 + r;
      resultsb[(size_t)ii * RK + h * 16 + (lane & 15)] =
          f2bf(c[r] * Zi[ii * 12 + h]);
    }
  } else {
    #pragma unroll
    for (int r = 0; r < 4; ++r) {
      const int ii = ibase + (lane >> 4) * 4 + r;
      cl[wvv][(lane >> 4) * 4 + r][lane & 15] = c[r] * Zi[ii * 12 + h];
    }
    __syncthreads();
    const int np = halfb ? 3 : 5;
    for (int t = tid; t < 64 * np; t += 256) {
      const int il = t / np, pl = t % np;
      const int p = halfb ? 5 + pl : pl;
      const int lc = p * 3 - (halfb ? 8 : 0);
      const int ii = it * 64 + il;
      const float a0 = cl[il >> 4][il & 15][lc + 0] - trans[ii * 3 + 0];
      const float a1 = cl[il >> 4][il & 15][lc + 1] - trans[ii * 3 + 1];
      const float a2 = cl[il >> 4][il & 15][lc + 2] - trans[ii * 3 + 2];
      const float* R = rot + ii * 9;
      const float o0 = a0 * R[0] + a1 * R[1] + a2 * R[2];
      const float o1 = a0 * R[3] + a1 * R[4] + a2 * R[5];
      const float o2 = a0 * R[6] + a1 * R[7] + a2 * R[8];
      unsigned short* rr = resultsb + (size_t)ii * RK;
      rr[192 + h * 24 + p * 3 + 0] = f2bf(o0);
      rr[192 + h * 24 + p * 3 + 1] = f2bf(o1);
      rr[192 + h * 24 + p * 3 + 2] = f2bf(o2);
      rr[480 + h * 8 + p] = f2bf(sqrtf(o0 * o0 + o1 * o1 + o2 * o2 + 1e-8f));
    }
  }
}

// ---------------- Kernel 5a: output GEMM via MFMA, K-split ------------------
__global__ __launch_bounds__(256) void k_outg(
    const unsigned short* __restrict__ resb, const unsigned short* __restrict__ WoT,
    float* __restrict__ partial)
{
  const int i0 = blockIdx.x * 64;
  const int c0 = blockIdx.y * 64;
  const int k0 = blockIdx.z * 544;
  const int wv = threadIdx.x >> 6, lane = threadIdx.x & 63;
  const int aRow = i0 + wv * 16 + (lane & 15);

  f32x4 acc0 = (f32x4){0.f, 0.f, 0.f, 0.f};
  f32x4 acc1 = (f32x4){0.f, 0.f, 0.f, 0.f};
  f32x4 acc2 = (f32x4){0.f, 0.f, 0.f, 0.f};
  f32x4 acc3 = (f32x4){0.f, 0.f, 0.f, 0.f};
  for (int ks = 0; ks < 17; ++ks) {
    const int kk = k0 + ks * 32 + (lane >> 4) * 8;
    const bf16x8 a = *(const bf16x8*)&resb[(size_t)aRow * RK + kk];
    const bf16x8 b0 = *(const bf16x8*)&WoT[(size_t)(c0 + 0 * 16 + (lane & 15)) * RK + kk];
    const bf16x8 b1 = *(const bf16x8*)&WoT[(size_t)(c0 + 1 * 16 + (lane & 15)) * RK + kk];
    const bf16x8 b2 = *(const bf16x8*)&WoT[(size_t)(c0 + 2 * 16 + (lane & 15)) * RK + kk];
    const bf16x8 b3 = *(const bf16x8*)&WoT[(size_t)(c0 + 3 * 16 + (lane & 15)) * RK + kk];
    acc0 = __builtin_amdgcn_mfma_f32_16x16x32_bf16(a, b0, acc0, 0, 0, 0);
    acc1 = __builtin_amdgcn_mfma_f32_16x16x32_bf16(a, b1, acc1, 0, 0, 0);
    acc2 = __builtin_amdgcn_mfma_f32_16x16x32_bf16(a, b2, acc2, 0, 0, 0);
    acc3 = __builtin_amdgcn_mfma_f32_16x16x32_bf16(a, b3, acc3, 0, 0, 0);
  }
  float* pbase = partial + (size_t)blockIdx.z * (LL * 384);
  #pragma unroll
  for (int r = 0; r < 4; ++r) {
    const int ii = i0 + wv * 16 + (lane >> 4) * 4 + r;
    float* prow = pbase + (size_t)ii * 384 + c0 + (lane & 15);
    prow[0]  = acc0[r];
    prow[16] = acc1[r];
    prow[32] = acc2[r];
    prow[48] = acc3[r];
  }
}

// ---------------- Kernel 5b: reduce partials + bias -------------------------
__global__ __launch_bounds__(256) void k_out2(
    const float* __restrict__ partial, const float* __restrict__ bout,
    float* __restrict__ out)
{
  const int e = blockIdx.x * 256 + threadIdx.x;
  const int c = e % 384;
  out[e] = bout[c] + partial[e] + partial[e + LL * 384]
         + partial[e + 2 * LL * 384] + partial[e + 3 * LL * 384];
}

extern "C" void kernel_launch(void* const* d_in, const int* in_sizes, int n_in,
                              void* d_out, int out_size, void* d_ws, size_t ws_size,
                              hipStream_t stream)
{
  const float* x     = (const float*)d_in[0];
  const float* prw   = (const float*)d_in[1];
  const float* rot   = (const float*)d_in[2];
  const float* trans = (const float*)d_in[3];
  const float* Ws    = (const float*)d_in[4];
  const float* Wp    = (const float*)d_in[5];
  const float* pw    = (const float*)d_in[6];
  const float* Wpair = (const float*)d_in[7];
  const float* bpair = (const float*)d_in[8];
  const float* Wout  = (const float*)d_in[9];
  const float* bout  = (const float*)d_in[10];

  float* ws = (float*)d_ws;
  unsigned short* qth = (unsigned short*)ws;                // 98304 f
  unsigned short* kth = (unsigned short*)(ws + 98304);      // 98304 f
  unsigned short* vsT = (unsigned short*)(ws + 196608);     // 49152 f
  unsigned short* vpT = (unsigned short*)(ws + 245760);     // 73728 f
  unsigned short* pb  = (unsigned short*)(ws + 319488);     // 1572864 f
  float* Zp      = ws + 1892352;                            // 98304 f
  float* Zi      = ws + 1990656;                            // 6144 f
  unsigned short* resultsb = (unsigned short*)(ws + 1996800); // 557056 f
  unsigned short* WoT = (unsigned short*)(ws + 2553856);    // 417792 f
  float* partial = ws + 2971648;                            // 786432 f
  unsigned short* xb = (unsigned short*)(ws + 3758080);     // 98304 f
  unsigned short* WcatT = (unsigned short*)(ws + 3856384);  // 221184 f
  float* rawq    = ws + 4077568;                            // 589824 f (ends 4667392)
  float* out     = (float*)d_out;

  k_prepx<<<96, 256, 0, stream>>>(x, xb);
  k_prepw<<<dim3(18, 6), 256, 0, stream>>>(Ws, Wp, WcatT);
  k_qkv_gemm<<<dim3(8, 72), 256, 0, stream>>>(xb, WcatT, rawq);
  k_post<<<128, 256, 0, stream>>>(rawq, rot, trans, pw, qth, kth, vsT, vpT);
  k_prep<<<dim3(33, 6), 256, 0, stream>>>(Wout, WoT, resultsb);
  k_logits<<<512, 512, 0, stream>>>(prw, Wpair, bpair, qth, kth, pb, Zp);
  k_pv<<<512, 512, 0, stream>>>(prw, pb, Zp, Zi, resultsb);
  k_sv<<<dim3(36, 8), 256, 0, stream>>>(pb, vsT, vpT, Zi, rot, trans, resultsb);
  k_outg<<<dim3(8, 6, 4), 256, 0, stream>>>(resultsb, WoT, partial);
  k_out2<<<768, 256, 0, stream>>>(partial, bout, out);
}

// Round 12
// 104.555 us; speedup vs baseline: 2.0280x; 1.0414x over previous
//
#include <hip/hip_runtime.h>
#include <hip/hip_bf16.h>
#include <math.h>

#define LL 512
#define HH 12
#define DM 384
#define DPAIR 128
#define RK 2176   /* padded K for output GEMM (2112 + 64) */

#define SCALAR_SCALE 0.14433756729740643f   /* (3*16)^-0.5 */
#define POINT_SCALE  0.13608276348795434f   /* (3*4*4.5)^-0.5 */
#define PAIR_SCALE   0.5773502691896258f    /* 3^-0.5 */

typedef short bf16x8 __attribute__((ext_vector_type(8)));
typedef float f32x4 __attribute__((ext_vector_type(4)));

__device__ __forceinline__ float softplusf(float w) {
  return (w > 20.f) ? w : log1pf(expf(w));
}
// native conversion: compiler can fuse pairs into v_cvt_pk_bf16_f32
__device__ __forceinline__ unsigned short f2bf(float f) {
  __hip_bfloat16 h = __float2bfloat16(f);
  return __builtin_bit_cast(unsigned short, h);
}

// ---------------- Kernel 0: all preprocessing in one dispatch ---------------
// blocks 0..95    : x -> bf16
// blocks 96..203  : Ws|Wp -> WcatT bf16 [1152][384]
// blocks 204..401 : Wout -> WoT bf16 [384][2176] + zero pads
__global__ __launch_bounds__(256) void k_preps(
    const float* __restrict__ x, const float* __restrict__ Ws,
    const float* __restrict__ Wp, const float* __restrict__ Wout,
    unsigned short* __restrict__ xb, unsigned short* __restrict__ WcatT,
    unsigned short* __restrict__ WoT, unsigned short* __restrict__ resultsb)
{
  const int bid = blockIdx.x;
  if (bid < 96) {
    const int t = bid * 256 + threadIdx.x;
    const float4 v0 = ((const float4*)x)[t * 2];
    const float4 v1 = ((const float4*)x)[t * 2 + 1];
    unsigned int w[4];
    w[0] = (unsigned)f2bf(v0.x) | ((unsigned)f2bf(v0.y) << 16);
    w[1] = (unsigned)f2bf(v0.z) | ((unsigned)f2bf(v0.w) << 16);
    w[2] = (unsigned)f2bf(v1.x) | ((unsigned)f2bf(v1.y) << 16);
    w[3] = (unsigned)f2bf(v1.z) | ((unsigned)f2bf(v1.w) << 16);
    *(uint4*)&xb[t * 8] = *(uint4*)w;
    return;
  }
  __shared__ unsigned short t[64][72];
  if (bid < 204) {
    const int b = bid - 96;
    const int c0 = (b % 18) * 64;
    const int k0 = (b / 18) * 64;
    const float* __restrict__ W = (c0 < 576) ? Ws : Wp;
    const int cb = (c0 < 576) ? c0 : c0 - 576;
    for (int idx = threadIdx.x; idx < 64 * 64; idx += 256) {
      const int r = idx >> 6, c = idx & 63;
      t[c][r] = f2bf(W[(size_t)(k0 + r) * 576 + cb + c]);
    }
    __syncthreads();
    for (int idx = threadIdx.x; idx < 64 * 64; idx += 256) {
      const int n = idx >> 6, k = idx & 63;
      WcatT[(size_t)(c0 + n) * 384 + k0 + k] = t[n][k];
    }
    return;
  }
  {
    const int b = bid - 204;
    const int kt = b % 33, ct = b / 33;
    const int k0 = kt * 64;
    const int c0 = ct * 64;
    for (int idx = threadIdx.x; idx < 64 * 64; idx += 256) {
      const int r = idx >> 6, c = idx & 63;
      t[c][r] = f2bf(Wout[(size_t)(k0 + r) * 384 + c0 + c]);
    }
    __syncthreads();
    for (int idx = threadIdx.x; idx < 64 * 64; idx += 256) {
      const int n = idx >> 6, k = idx & 63;
      WoT[(size_t)(c0 + n) * RK + k0 + k] = t[n][k];
    }
    if (kt == 0) {   // WoT k-pad
      for (int idx = threadIdx.x; idx < 64 * 64; idx += 256) {
        const int n = idx >> 6, k = idx & 63;
        WoT[(size_t)(c0 + n) * RK + 2112 + k] = 0;
      }
    }
    if (ct == 0 && kt < 8) {   // resultsb col-pad
      const int i0 = kt * 64;
      for (int idx = threadIdx.x; idx < 64 * 64; idx += 256) {
        const int r = idx >> 6, c = idx & 63;
        resultsb[(size_t)(i0 + r) * RK + 2112 + c] = 0;
      }
    }
  }
}

// ---------------- Kernel 1: QKV projection via MFMA --------------------------
// grid (8 i-tiles of 64, 72 c-tiles of 16), 256 thr (4 waves = 4 i-subtiles).
__global__ __launch_bounds__(256) void k_qkv_gemm(
    const unsigned short* __restrict__ xb, const unsigned short* __restrict__ WcatT,
    float* __restrict__ rawq)
{
  const int i0 = blockIdx.x * 64;
  const int c0 = blockIdx.y * 16;
  const int wv = threadIdx.x >> 6, lane = threadIdx.x & 63;
  const int aRow = i0 + wv * 16 + (lane & 15);
  const int kg = lane >> 4;

  f32x4 acc = (f32x4){0.f, 0.f, 0.f, 0.f};
  const unsigned short* arow = xb + (size_t)aRow * DM + kg * 8;
  const unsigned short* brow = WcatT + (size_t)(c0 + (lane & 15)) * DM + kg * 8;
  #pragma unroll
  for (int ks = 0; ks < 12; ks += 2) {
    const bf16x8 a0 = *(const bf16x8*)(arow + ks * 32);
    const bf16x8 b0 = *(const bf16x8*)(brow + ks * 32);
    const bf16x8 a1 = *(const bf16x8*)(arow + (ks + 1) * 32);
    const bf16x8 b1 = *(const bf16x8*)(brow + (ks + 1) * 32);
    acc = __builtin_amdgcn_mfma_f32_16x16x32_bf16(a0, b0, acc, 0, 0, 0);
    acc = __builtin_amdgcn_mfma_f32_16x16x32_bf16(a1, b1, acc, 0, 0, 0);
  }
  #pragma unroll
  for (int q = 0; q < 4; ++q) {
    const int ii = i0 + wv * 16 + (lane >> 4) * 4 + q;
    rawq[(size_t)ii * 1152 + c0 + (lane & 15)] = acc[q];
  }
}

// ---------------- Kernel 1c: rotation/translation + extended vectors --------
__global__ __launch_bounds__(256) void k_post(
    const float* __restrict__ rawq, const float* __restrict__ rot,
    const float* __restrict__ trans, const float* __restrict__ pwraw,
    unsigned short* __restrict__ qth, unsigned short* __restrict__ kth,
    unsigned short* __restrict__ vsT, unsigned short* __restrict__ vpT)
{
  __shared__ float qnl[4][12][4], knl[4][12][4];
  const int l0 = blockIdx.x * 4;

  // scalar half: cols 0..575
  for (int t = threadIdx.x; t < 4 * 576; t += 256) {
    const int r = t / 576, col = t % 576;
    const float v = rawq[(size_t)(l0 + r) * 1152 + col];
    const int part = col / 192;
    const int h = (col % 192) / 16;
    const int d = col % 16;
    if (part == 0)
      qth[(size_t)(h * LL + l0 + r) * 32 + d] = f2bf(SCALAR_SCALE * v);
    else if (part == 1)
      kth[(size_t)(h * LL + l0 + r) * 32 + d] = f2bf(v);
    else
      vsT[(size_t)(h * 16 + d) * LL + l0 + r] = f2bf(v);
  }
  // point half: cols 576..1151 (hp*3 + axis, hp = h*16+p)
  for (int t = threadIdx.x; t < 4 * 192; t += 256) {
    const int r = t / 192, hp = t % 192;
    const int h = hp >> 4, p = hp & 15;
    const int l = l0 + r;
    const float* rr = rawq + (size_t)l * 1152 + 576 + hp * 3;
    const float c0 = rr[0], c1 = rr[1], c2 = rr[2];
    const float* R = rot + l * 9;
    const float o0 = c0 * R[0] + c1 * R[3] + c2 * R[6] + trans[l * 3 + 0];
    const float o1 = c0 * R[1] + c1 * R[4] + c2 * R[7] + trans[l * 3 + 1];
    const float o2 = c0 * R[2] + c1 * R[5] + c2 * R[8] + trans[l * 3 + 2];
    if (p < 4) {
      const size_t base = (size_t)(h * LL + l) * 32 + 16 + p * 3;
      qth[base + 0] = f2bf(o0);
      qth[base + 1] = f2bf(o1);
      qth[base + 2] = f2bf(o2);
      qnl[r][h][p] = o0 * o0 + o1 * o1 + o2 * o2;
    } else if (p < 8) {
      const float Ch = -0.5f * POINT_SCALE * softplusf(pwraw[h]);
      const size_t base = (size_t)(h * LL + l) * 32 + 16 + (p - 4) * 3;
      kth[base + 0] = f2bf(-2.f * Ch * o0);
      kth[base + 1] = f2bf(-2.f * Ch * o1);
      kth[base + 2] = f2bf(-2.f * Ch * o2);
      knl[r][h][p - 4] = o0 * o0 + o1 * o1 + o2 * o2;
    } else {
      const int pp = p - 8;
      const size_t base = (size_t)(h * 24 + pp * 3) * LL + l;
      vpT[base + 0 * LL] = f2bf(o0);
      vpT[base + 1 * LL] = f2bf(o1);
      vpT[base + 2 * LL] = f2bf(o2);
    }
  }
  __syncthreads();
  if (threadIdx.x < 48) {
    const int r = threadIdx.x / 12, h = threadIdx.x % 12;
    const int l = l0 + r;
    const float qsum = qnl[r][h][0] + qnl[r][h][1] + qnl[r][h][2] + qnl[r][h][3];
    const float ksum = knl[r][h][0] + knl[r][h][1] + knl[r][h][2] + knl[r][h][3];
    const float Ch = -0.5f * POINT_SCALE * softplusf(pwraw[h]);
    const size_t qb = (size_t)(h * LL + l) * 32;
    qth[qb + 28] = f2bf(qsum);
    qth[qb + 29] = f2bf(1.f);
    qth[qb + 30] = 0; qth[qb + 31] = 0;
    kth[qb + 28] = f2bf(Ch);
    kth[qb + 29] = f2bf(Ch * ksum);
    kth[qb + 30] = 0; kth[qb + 31] = 0;
  }
}

// ---------------- Kernel 2: logits via MFMA -> p = exp(l) + Z partials ------
// grid 512 (32 i-tiles x 16 j-tiles of 32), 512 thr. One PR pass (HBM).
__global__ __launch_bounds__(512) void k_logits(
    const float* __restrict__ pr, const float* __restrict__ Wpair,
    const float* __restrict__ bpair, const unsigned short* __restrict__ qth,
    const unsigned short* __restrict__ kth, unsigned short* __restrict__ pb,
    float* __restrict__ Zp)
{
  __shared__ float ltile[512 * 13];
  __shared__ __align__(16) unsigned short wTb[16 * 128];
  __shared__ float bpl[12];
  const int tid = threadIdx.x;
  const int wv = tid >> 6, lane = tid & 63;
  const int i0 = (blockIdx.x >> 4) * 16;
  const int jb = blockIdx.x & 15;
  const int j0 = jb * 32;

  for (int t = tid; t < 16 * 128; t += 512) {
    const int h = t >> 7, k = t & 127;
    wTb[t] = (h < HH) ? f2bf(Wpair[k * HH + h]) : (unsigned short)0;
  }
  if (tid < 12) bpl[tid] = bpair[tid];
  __syncthreads();

  bf16x8 bfrag[4];
  {
    const int bh = lane & 15, ch = lane >> 4;
    #pragma unroll
    for (int s = 0; s < 4; ++s)
      bfrag[s] = *(const bf16x8*)&wTb[bh * 128 + s * 32 + ch * 8];
  }

  // pair-bias: A rows = (ii,jj) pairs; two chains (tb, tb+16) per iteration
  for (int tb = wv; tb < 16; tb += 8) {
    const int pi0 = tb * 16 + (lane & 15);
    const int pi1 = (tb + 16) * 16 + (lane & 15);
    const float* arow0 = pr + ((size_t)(i0 + (pi0 >> 5)) * LL + j0 + (pi0 & 31)) * DPAIR
                         + (lane >> 4) * 8;
    const float* arow1 = pr + ((size_t)(i0 + (pi1 >> 5)) * LL + j0 + (pi1 & 31)) * DPAIR
                         + (lane >> 4) * 8;
    f32x4 c0 = (f32x4){0.f, 0.f, 0.f, 0.f};
    f32x4 c1 = (f32x4){0.f, 0.f, 0.f, 0.f};
    #pragma unroll
    for (int s = 0; s < 4; ++s) {
      const float4 u0 = *(const float4*)(arow0 + s * 32);
      const float4 u1 = *(const float4*)(arow0 + s * 32 + 4);
      const float4 v0 = *(const float4*)(arow1 + s * 32);
      const float4 v1 = *(const float4*)(arow1 + s * 32 + 4);
      bf16x8 a0, a1;
      a0[0] = (short)f2bf(u0.x); a0[1] = (short)f2bf(u0.y);
      a0[2] = (short)f2bf(u0.z); a0[3] = (short)f2bf(u0.w);
      a0[4] = (short)f2bf(u1.x); a0[5] = (short)f2bf(u1.y);
      a0[6] = (short)f2bf(u1.z); a0[7] = (short)f2bf(u1.w);
      a1[0] = (short)f2bf(v0.x); a1[1] = (short)f2bf(v0.y);
      a1[2] = (short)f2bf(v0.z); a1[3] = (short)f2bf(v0.w);
      a1[4] = (short)f2bf(v1.x); a1[5] = (short)f2bf(v1.y);
      a1[6] = (short)f2bf(v1.z); a1[7] = (short)f2bf(v1.w);
      c0 = __builtin_amdgcn_mfma_f32_16x16x32_bf16(a0, bfrag[s], c0, 0, 0, 0);
      c1 = __builtin_amdgcn_mfma_f32_16x16x32_bf16(a1, bfrag[s], c1, 0, 0, 0);
    }
    const int hcol = lane & 15;
    if (hcol < HH) {
      #pragma unroll
      for (int q = 0; q < 4; ++q) {
        ltile[(tb * 16 + (lane >> 4) * 4 + q) * 13 + hcol] = c0[q];
        ltile[((tb + 16) * 16 + (lane >> 4) * 4 + q) * 13 + hcol] = c1[q];
      }
    }
  }
  __syncthreads();

  // qk-extended GEMM + assemble + exp -> pb (bf16), p back into ltile
  for (int task = wv; task < 24; task += 8) {
    const int h = task >> 1, jb2 = task & 1;
    const bf16x8 a = *(const bf16x8*)&qth[(size_t)(h * LL + i0 + (lane & 15)) * 32
                                          + (lane >> 4) * 8];
    const bf16x8 b = *(const bf16x8*)&kth[(size_t)(h * LL + j0 + jb2 * 16 + (lane & 15)) * 32
                                          + (lane >> 4) * 8];
    f32x4 c = (f32x4){0.f, 0.f, 0.f, 0.f};
    c = __builtin_amdgcn_mfma_f32_16x16x32_bf16(a, b, c, 0, 0, 0);
    const int j = jb2 * 16 + (lane & 15);
    #pragma unroll
    for (int q = 0; q < 4; ++q) {
      const int ii = (lane >> 4) * 4 + q;
      const float bias = ltile[(ii * 32 + j) * 13 + h];
      const float l = c[q] + PAIR_SCALE * (bias + bpl[h]);
      const float p = __expf(l);
      pb[(size_t)(i0 + ii) * 6144 + h * 512 + j0 + j] = f2bf(p);
      ltile[(ii * 32 + j) * 13 + h] = p;   // same thread re-writes its own slot
    }
  }
  __syncthreads();

  // Z partials: owner thread per (ii,h), deterministic
  if (tid < 192) {
    const int ii = tid / 12, h = tid % 12;
    float s = 0.f;
    for (int j = 0; j < 32; ++j) s += ltile[(ii * 32 + j) * 13 + h];
    Zp[((size_t)jb * LL + i0 + ii) * 12 + h] = s;
  }
}

// ---------------- Kernel 3: res_pair PV, transposed (no LDS transpose) -----
// grid 512 (one block per i), 512 thr (8 waves = 8 d-tiles of 16).
__global__ __launch_bounds__(512) void k_pv(
    const float* __restrict__ pr, const unsigned short* __restrict__ pb,
    const float* __restrict__ Zp, float* __restrict__ Zi,
    unsigned short* __restrict__ resultsb)
{
  __shared__ __align__(16) unsigned short attn_lds[16 * 544];
  __shared__ float zz[12];
  const int i = blockIdx.x;
  const int tid = threadIdx.x;
  const int wv = tid >> 6, lane = tid & 63;

  // stage p row [12][512] bf16 via uint4; zero rows 12..15
  const uint4* src = (const uint4*)(pb + (size_t)i * 6144);
  for (int t = tid; t < 768; t += 512) {
    const int h = t >> 6, c8 = t & 63;
    *(uint4*)&attn_lds[h * 544 + c8 * 8] = src[t];
  }
  for (int t = tid; t < 272; t += 512)
    *(uint4*)&attn_lds[12 * 544 + t * 8] = (uint4){0, 0, 0, 0};
  if (tid < 12) {
    float s = 0.f;
    #pragma unroll
    for (int jb = 0; jb < 16; ++jb) s += Zp[((size_t)jb * LL + i) * 12 + tid];
    const float r = 1.f / s;
    zz[tid] = r;
    Zi[i * 12 + tid] = r;
  }
  __syncthreads();

  const int d0 = wv * 16;                 // this wave's d-tile
  const int dl = lane & 15;               // A row = d_local
  const int kg = lane >> 4;               // k-group
  const float* __restrict__ base = pr + (size_t)i * (LL * DPAIR) + d0 + dl;

  f32x4 c = (f32x4){0.f, 0.f, 0.f, 0.f};
  for (int ks = 0; ks < 16; ks += 2) {    // k = j, 64 per double-step
    const int j0a = ks * 32 + kg * 8;
    const int j0b = j0a + 32;
    float ra[8], rb[8];
    #pragma unroll
    for (int e = 0; e < 8; ++e) ra[e] = base[(size_t)(j0a + e) * DPAIR];
    #pragma unroll
    for (int e = 0; e < 8; ++e) rb[e] = base[(size_t)(j0b + e) * DPAIR];
    bf16x8 a0, a1;
    #pragma unroll
    for (int e = 0; e < 8; ++e) { a0[e] = (short)f2bf(ra[e]); a1[e] = (short)f2bf(rb[e]); }
    const bf16x8 b0 = *(const bf16x8*)&attn_lds[(lane & 15) * 544 + ks * 32 + kg * 8];
    const bf16x8 b1 = *(const bf16x8*)&attn_lds[(lane & 15) * 544 + (ks + 1) * 32 + kg * 8];
    c = __builtin_amdgcn_mfma_f32_16x16x32_bf16(a0, b0, c, 0, 0, 0);
    c = __builtin_amdgcn_mfma_f32_16x16x32_bf16(a1, b1, c, 0, 0, 0);
  }
  // D: col = lane&15 = h, row = (lane>>4)*4+q = d_local
  const int h = lane & 15;
  if (h < HH) {
    const float zv = zz[h];
    #pragma unroll
    for (int q = 0; q < 4; ++q) {
      const int d = d0 + (lane >> 4) * 4 + q;
      resultsb[(size_t)i * RK + 576 + h * 128 + d] = f2bf(c[q] * zv);
    }
  }
}

// ---------------- Kernel 4: res_s / res_p via Q-tiled MFMA ------------------
// grid (36 col-blocks, 8 i-tiles), 256 thr (4 waves = 4 M-tiles of 16 i).
__global__ __launch_bounds__(256) void k_sv(
    const unsigned short* __restrict__ pb, const unsigned short* __restrict__ vsT,
    const unsigned short* __restrict__ vpT, const float* __restrict__ Zi,
    const float* __restrict__ rot, const float* __restrict__ trans,
    unsigned short* __restrict__ resultsb)
{
  __shared__ float cl[4][16][16];
  const int cb = blockIdx.x;
  const int it = blockIdx.y;
  const int tid = threadIdx.x;
  const int wvv = tid >> 6, lane = tid & 63;
  int h, rowbase, isvp = 0, halfb = 0;
  if (cb < 12) { h = cb; rowbase = h * 16; }
  else { const int v = cb - 12; h = v >> 1; halfb = v & 1; isvp = 1;
         rowbase = h * 24 + halfb * 8; }
  const unsigned short* __restrict__ vT = isvp ? vpT : vsT;
  const int ibase = it * 64 + wvv * 16;

  f32x4 c = (f32x4){0.f, 0.f, 0.f, 0.f};
  for (int ks = 0; ks < 16; ++ks) {
    const bf16x8 a = *(const bf16x8*)&pb[(size_t)(ibase + (lane & 15)) * 6144
                                         + h * 512 + ks * 32 + (lane >> 4) * 8];
    const bf16x8 b = *(const bf16x8*)&vT[(size_t)(rowbase + (lane & 15)) * LL
                                         + ks * 32 + (lane >> 4) * 8];
    c = __builtin_amdgcn_mfma_f32_16x16x32_bf16(a, b, c, 0, 0, 0);
  }
  if (!isvp) {
    #pragma unroll
    for (int r = 0; r < 4; ++r) {
      const int ii = ibase + (lane >> 4) * 4 + r;
      resultsb[(size_t)ii * RK + h * 16 + (lane & 15)] =
          f2bf(c[r] * Zi[ii * 12 + h]);
    }
  } else {
    #pragma unroll
    for (int r = 0; r < 4; ++r) {
      const int ii = ibase + (lane >> 4) * 4 + r;
      cl[wvv][(lane >> 4) * 4 + r][lane & 15] = c[r] * Zi[ii * 12 + h];
    }
    __syncthreads();
    const int np = halfb ? 3 : 5;
    for (int t = tid; t < 64 * np; t += 256) {
      const int il = t / np, pl = t % np;
      const int p = halfb ? 5 + pl : pl;
      const int lc = p * 3 - (halfb ? 8 : 0);
      const int ii = it * 64 + il;
      const float a0 = cl[il >> 4][il & 15][lc + 0] - trans[ii * 3 + 0];
      const float a1 = cl[il >> 4][il & 15][lc + 1] - trans[ii * 3 + 1];
      const float a2 = cl[il >> 4][il & 15][lc + 2] - trans[ii * 3 + 2];
      const float* R = rot + ii * 9;
      const float o0 = a0 * R[0] + a1 * R[1] + a2 * R[2];
      const float o1 = a0 * R[3] + a1 * R[4] + a2 * R[5];
      const float o2 = a0 * R[6] + a1 * R[7] + a2 * R[8];
      unsigned short* rr = resultsb + (size_t)ii * RK;
      rr[192 + h * 24 + p * 3 + 0] = f2bf(o0);
      rr[192 + h * 24 + p * 3 + 1] = f2bf(o1);
      rr[192 + h * 24 + p * 3 + 2] = f2bf(o2);
      rr[480 + h * 8 + p] = f2bf(sqrtf(o0 * o0 + o1 * o1 + o2 * o2 + 1e-8f));
    }
  }
}

// ---------------- Kernel 5a: output GEMM via MFMA, K-split ------------------
// grid (8 i-tiles, 12 c-tiles of 32, 4 K-splits of 544), 256 thr.
__global__ __launch_bounds__(256) void k_outg(
    const unsigned short* __restrict__ resb, const unsigned short* __restrict__ WoT,
    float* __restrict__ partial)
{
  const int i0 = blockIdx.x * 64;
  const int c0 = blockIdx.y * 32;
  const int k0 = blockIdx.z * 544;
  const int wv = threadIdx.x >> 6, lane = threadIdx.x & 63;
  const int aRow = i0 + wv * 16 + (lane & 15);

  f32x4 acc0 = (f32x4){0.f, 0.f, 0.f, 0.f};
  f32x4 acc1 = (f32x4){0.f, 0.f, 0.f, 0.f};
  for (int ks = 0; ks < 17; ++ks) {
    const int kk = k0 + ks * 32 + (lane >> 4) * 8;
    const bf16x8 a = *(const bf16x8*)&resb[(size_t)aRow * RK + kk];
    const bf16x8 b0 = *(const bf16x8*)&WoT[(size_t)(c0 + (lane & 15)) * RK + kk];
    const bf16x8 b1 = *(const bf16x8*)&WoT[(size_t)(c0 + 16 + (lane & 15)) * RK + kk];
    acc0 = __builtin_amdgcn_mfma_f32_16x16x32_bf16(a, b0, acc0, 0, 0, 0);
    acc1 = __builtin_amdgcn_mfma_f32_16x16x32_bf16(a, b1, acc1, 0, 0, 0);
  }
  float* pbase = partial + (size_t)blockIdx.z * (LL * 384);
  #pragma unroll
  for (int r = 0; r < 4; ++r) {
    const int ii = i0 + wv * 16 + (lane >> 4) * 4 + r;
    float* prow = pbase + (size_t)ii * 384 + c0 + (lane & 15);
    prow[0]  = acc0[r];
    prow[16] = acc1[r];
  }
}

// ---------------- Kernel 5b: reduce partials + bias -------------------------
__global__ __launch_bounds__(256) void k_out2(
    const float* __restrict__ partial, const float* __restrict__ bout,
    float* __restrict__ out)
{
  const int e = blockIdx.x * 256 + threadIdx.x;
  const int c = e % 384;
  out[e] = bout[c] + partial[e] + partial[e + LL * 384]
         + partial[e + 2 * LL * 384] + partial[e + 3 * LL * 384];
}

extern "C" void kernel_launch(void* const* d_in, const int* in_sizes, int n_in,
                              void* d_out, int out_size, void* d_ws, size_t ws_size,
                              hipStream_t stream)
{
  const float* x     = (const float*)d_in[0];
  const float* prw   = (const float*)d_in[1];
  const float* rot   = (const float*)d_in[2];
  const float* trans = (const float*)d_in[3];
  const float* Ws    = (const float*)d_in[4];
  const float* Wp    = (const float*)d_in[5];
  const float* pw    = (const float*)d_in[6];
  const float* Wpair = (const float*)d_in[7];
  const float* bpair = (const float*)d_in[8];
  const float* Wout  = (const float*)d_in[9];
  const float* bout  = (const float*)d_in[10];

  float* ws = (float*)d_ws;
  unsigned short* qth = (unsigned short*)ws;                // 98304 f
  unsigned short* kth = (unsigned short*)(ws + 98304);      // 98304 f
  unsigned short* vsT = (unsigned short*)(ws + 196608);     // 49152 f
  unsigned short* vpT = (unsigned short*)(ws + 245760);     // 73728 f
  unsigned short* pb  = (unsigned short*)(ws + 319488);     // 1572864 f
  float* Zp      = ws + 1892352;                            // 98304 f
  float* Zi      = ws + 1990656;                            // 6144 f
  unsigned short* resultsb = (unsigned short*)(ws + 1996800); // 557056 f
  unsigned short* WoT = (unsigned short*)(ws + 2553856);    // 417792 f
  float* partial = ws + 2971648;                            // 786432 f
  unsigned short* xb = (unsigned short*)(ws + 3758080);     // 98304 f
  unsigned short* WcatT = (unsigned short*)(ws + 3856384);  // 221184 f
  float* rawq    = ws + 4077568;                            // 589824 f (ends 4667392)
  float* out     = (float*)d_out;

  k_preps<<<402, 256, 0, stream>>>(x, Ws, Wp, Wout, xb, WcatT, WoT, resultsb);
  k_qkv_gemm<<<dim3(8, 72), 256, 0, stream>>>(xb, WcatT, rawq);
  k_post<<<128, 256, 0, stream>>>(rawq, rot, trans, pw, qth, kth, vsT, vpT);
  k_logits<<<512, 512, 0, stream>>>(prw, Wpair, bpair, qth, kth, pb, Zp);
  k_pv<<<512, 512, 0, stream>>>(prw, pb, Zp, Zi, resultsb);
  k_sv<<<dim3(36, 8), 256, 0, stream>>>(pb, vsT, vpT, Zi, rot, trans, resultsb);
  k_outg<<<dim3(8, 12, 4), 256, 0, stream>>>(resultsb, WoT, partial);
  k_out2<<<768, 256, 0, stream>>>(partial, bout, out);
}

// Round 13
// 100.936 us; speedup vs baseline: 2.1007x; 1.0359x over previous
//
#include <hip/hip_runtime.h>
#include <hip/hip_bf16.h>
#include <math.h>

#define LL 512
#define HH 12
#define DM 384
#define DPAIR 128
#define RK 2176   /* padded K for output GEMM (2112 + 64) */

#define SCALAR_SCALE 0.14433756729740643f   /* (3*16)^-0.5 */
#define POINT_SCALE  0.13608276348795434f   /* (3*4*4.5)^-0.5 */
#define PAIR_SCALE   0.5773502691896258f    /* 3^-0.5 */

typedef short bf16x8 __attribute__((ext_vector_type(8)));
typedef float f32x4 __attribute__((ext_vector_type(4)));

__device__ __forceinline__ float softplusf(float w) {
  return (w > 20.f) ? w : log1pf(expf(w));
}
// native conversion: compiler can fuse pairs into v_cvt_pk_bf16_f32
__device__ __forceinline__ unsigned short f2bf(float f) {
  __hip_bfloat16 h = __float2bfloat16(f);
  return __builtin_bit_cast(unsigned short, h);
}

// ---------------- Kernel 0: all preprocessing in one dispatch ---------------
// blocks 0..95    : x -> bf16
// blocks 96..203  : Ws|Wp -> WcatT bf16 [1152][384]
// blocks 204..401 : Wout -> WoT bf16 [384][2176] + zero pads
__global__ __launch_bounds__(256) void k_preps(
    const float* __restrict__ x, const float* __restrict__ Ws,
    const float* __restrict__ Wp, const float* __restrict__ Wout,
    unsigned short* __restrict__ xb, unsigned short* __restrict__ WcatT,
    unsigned short* __restrict__ WoT, unsigned short* __restrict__ resultsb)
{
  const int bid = blockIdx.x;
  if (bid < 96) {
    const int t = bid * 256 + threadIdx.x;
    const float4 v0 = ((const float4*)x)[t * 2];
    const float4 v1 = ((const float4*)x)[t * 2 + 1];
    unsigned int w[4];
    w[0] = (unsigned)f2bf(v0.x) | ((unsigned)f2bf(v0.y) << 16);
    w[1] = (unsigned)f2bf(v0.z) | ((unsigned)f2bf(v0.w) << 16);
    w[2] = (unsigned)f2bf(v1.x) | ((unsigned)f2bf(v1.y) << 16);
    w[3] = (unsigned)f2bf(v1.z) | ((unsigned)f2bf(v1.w) << 16);
    *(uint4*)&xb[t * 8] = *(uint4*)w;
    return;
  }
  __shared__ unsigned short t[64][72];
  if (bid < 204) {
    const int b = bid - 96;
    const int c0 = (b % 18) * 64;
    const int k0 = (b / 18) * 64;
    const float* __restrict__ W = (c0 < 576) ? Ws : Wp;
    const int cb = (c0 < 576) ? c0 : c0 - 576;
    for (int idx = threadIdx.x; idx < 64 * 64; idx += 256) {
      const int r = idx >> 6, c = idx & 63;
      t[c][r] = f2bf(W[(size_t)(k0 + r) * 576 + cb + c]);
    }
    __syncthreads();
    for (int idx = threadIdx.x; idx < 64 * 64; idx += 256) {
      const int n = idx >> 6, k = idx & 63;
      WcatT[(size_t)(c0 + n) * 384 + k0 + k] = t[n][k];
    }
    return;
  }
  {
    const int b = bid - 204;
    const int kt = b % 33, ct = b / 33;
    const int k0 = kt * 64;
    const int c0 = ct * 64;
    for (int idx = threadIdx.x; idx < 64 * 64; idx += 256) {
      const int r = idx >> 6, c = idx & 63;
      t[c][r] = f2bf(Wout[(size_t)(k0 + r) * 384 + c0 + c]);
    }
    __syncthreads();
    for (int idx = threadIdx.x; idx < 64 * 64; idx += 256) {
      const int n = idx >> 6, k = idx & 63;
      WoT[(size_t)(c0 + n) * RK + k0 + k] = t[n][k];
    }
    if (kt == 0) {   // WoT k-pad
      for (int idx = threadIdx.x; idx < 64 * 64; idx += 256) {
        const int n = idx >> 6, k = idx & 63;
        WoT[(size_t)(c0 + n) * RK + 2112 + k] = 0;
      }
    }
    if (ct == 0 && kt < 8) {   // resultsb col-pad
      const int i0 = kt * 64;
      for (int idx = threadIdx.x; idx < 64 * 64; idx += 256) {
        const int r = idx >> 6, c = idx & 63;
        resultsb[(size_t)(i0 + r) * RK + 2112 + c] = 0;
      }
    }
  }
}

// ---------------- Kernel 1: QKV projection via MFMA --------------------------
__global__ __launch_bounds__(256) void k_qkv_gemm(
    const unsigned short* __restrict__ xb, const unsigned short* __restrict__ WcatT,
    float* __restrict__ rawq)
{
  const int i0 = blockIdx.x * 64;
  const int c0 = blockIdx.y * 16;
  const int wv = threadIdx.x >> 6, lane = threadIdx.x & 63;
  const int aRow = i0 + wv * 16 + (lane & 15);
  const int kg = lane >> 4;

  f32x4 acc = (f32x4){0.f, 0.f, 0.f, 0.f};
  const unsigned short* arow = xb + (size_t)aRow * DM + kg * 8;
  const unsigned short* brow = WcatT + (size_t)(c0 + (lane & 15)) * DM + kg * 8;
  #pragma unroll
  for (int ks = 0; ks < 12; ks += 2) {
    const bf16x8 a0 = *(const bf16x8*)(arow + ks * 32);
    const bf16x8 b0 = *(const bf16x8*)(brow + ks * 32);
    const bf16x8 a1 = *(const bf16x8*)(arow + (ks + 1) * 32);
    const bf16x8 b1 = *(const bf16x8*)(brow + (ks + 1) * 32);
    acc = __builtin_amdgcn_mfma_f32_16x16x32_bf16(a0, b0, acc, 0, 0, 0);
    acc = __builtin_amdgcn_mfma_f32_16x16x32_bf16(a1, b1, acc, 0, 0, 0);
  }
  #pragma unroll
  for (int q = 0; q < 4; ++q) {
    const int ii = i0 + wv * 16 + (lane >> 4) * 4 + q;
    rawq[(size_t)ii * 1152 + c0 + (lane & 15)] = acc[q];
  }
}

// ---------------- Kernel 1c: rotation/translation + extended vectors --------
__global__ __launch_bounds__(256) void k_post(
    const float* __restrict__ rawq, const float* __restrict__ rot,
    const float* __restrict__ trans, const float* __restrict__ pwraw,
    unsigned short* __restrict__ qth, unsigned short* __restrict__ kth,
    unsigned short* __restrict__ vsT, unsigned short* __restrict__ vpT)
{
  __shared__ float qnl[4][12][4], knl[4][12][4];
  const int l0 = blockIdx.x * 4;

  // scalar half: cols 0..575
  for (int t = threadIdx.x; t < 4 * 576; t += 256) {
    const int r = t / 576, col = t % 576;
    const float v = rawq[(size_t)(l0 + r) * 1152 + col];
    const int part = col / 192;
    const int h = (col % 192) / 16;
    const int d = col % 16;
    if (part == 0)
      qth[(size_t)(h * LL + l0 + r) * 32 + d] = f2bf(SCALAR_SCALE * v);
    else if (part == 1)
      kth[(size_t)(h * LL + l0 + r) * 32 + d] = f2bf(v);
    else
      vsT[(size_t)(h * 16 + d) * LL + l0 + r] = f2bf(v);
  }
  // point half: cols 576..1151 (hp*3 + axis, hp = h*16+p)
  for (int t = threadIdx.x; t < 4 * 192; t += 256) {
    const int r = t / 192, hp = t % 192;
    const int h = hp >> 4, p = hp & 15;
    const int l = l0 + r;
    const float* rr = rawq + (size_t)l * 1152 + 576 + hp * 3;
    const float c0 = rr[0], c1 = rr[1], c2 = rr[2];
    const float* R = rot + l * 9;
    const float o0 = c0 * R[0] + c1 * R[3] + c2 * R[6] + trans[l * 3 + 0];
    const float o1 = c0 * R[1] + c1 * R[4] + c2 * R[7] + trans[l * 3 + 1];
    const float o2 = c0 * R[2] + c1 * R[5] + c2 * R[8] + trans[l * 3 + 2];
    if (p < 4) {
      const size_t base = (size_t)(h * LL + l) * 32 + 16 + p * 3;
      qth[base + 0] = f2bf(o0);
      qth[base + 1] = f2bf(o1);
      qth[base + 2] = f2bf(o2);
      qnl[r][h][p] = o0 * o0 + o1 * o1 + o2 * o2;
    } else if (p < 8) {
      const float Ch = -0.5f * POINT_SCALE * softplusf(pwraw[h]);
      const size_t base = (size_t)(h * LL + l) * 32 + 16 + (p - 4) * 3;
      kth[base + 0] = f2bf(-2.f * Ch * o0);
      kth[base + 1] = f2bf(-2.f * Ch * o1);
      kth[base + 2] = f2bf(-2.f * Ch * o2);
      knl[r][h][p - 4] = o0 * o0 + o1 * o1 + o2 * o2;
    } else {
      const int pp = p - 8;
      const size_t base = (size_t)(h * 24 + pp * 3) * LL + l;
      vpT[base + 0 * LL] = f2bf(o0);
      vpT[base + 1 * LL] = f2bf(o1);
      vpT[base + 2 * LL] = f2bf(o2);
    }
  }
  __syncthreads();
  if (threadIdx.x < 48) {
    const int r = threadIdx.x / 12, h = threadIdx.x % 12;
    const int l = l0 + r;
    const float qsum = qnl[r][h][0] + qnl[r][h][1] + qnl[r][h][2] + qnl[r][h][3];
    const float ksum = knl[r][h][0] + knl[r][h][1] + knl[r][h][2] + knl[r][h][3];
    const float Ch = -0.5f * POINT_SCALE * softplusf(pwraw[h]);
    const size_t qb = (size_t)(h * LL + l) * 32;
    qth[qb + 28] = f2bf(qsum);
    qth[qb + 29] = f2bf(1.f);
    qth[qb + 30] = 0; qth[qb + 31] = 0;
    kth[qb + 28] = f2bf(Ch);
    kth[qb + 29] = f2bf(Ch * ksum);
    kth[qb + 30] = 0; kth[qb + 31] = 0;
  }
}

// ---------------- Kernel 2: logits via MFMA -> p = exp(l) + Z partials ------
__global__ __launch_bounds__(512) void k_logits(
    const float* __restrict__ pr, const float* __restrict__ Wpair,
    const float* __restrict__ bpair, const unsigned short* __restrict__ qth,
    const unsigned short* __restrict__ kth, unsigned short* __restrict__ pb,
    float* __restrict__ Zp)
{
  __shared__ float ltile[512 * 13];
  __shared__ __align__(16) unsigned short wTb[16 * 128];
  __shared__ float bpl[12];
  const int tid = threadIdx.x;
  const int wv = tid >> 6, lane = tid & 63;
  const int i0 = (blockIdx.x >> 4) * 16;
  const int jb = blockIdx.x & 15;
  const int j0 = jb * 32;

  for (int t = tid; t < 16 * 128; t += 512) {
    const int h = t >> 7, k = t & 127;
    wTb[t] = (h < HH) ? f2bf(Wpair[k * HH + h]) : (unsigned short)0;
  }
  if (tid < 12) bpl[tid] = bpair[tid];
  __syncthreads();

  bf16x8 bfrag[4];
  {
    const int bh = lane & 15, ch = lane >> 4;
    #pragma unroll
    for (int s = 0; s < 4; ++s)
      bfrag[s] = *(const bf16x8*)&wTb[bh * 128 + s * 32 + ch * 8];
  }

  // pair-bias: A rows = (ii,jj) pairs; two chains (tb, tb+16) per iteration
  for (int tb = wv; tb < 16; tb += 8) {
    const int pi0 = tb * 16 + (lane & 15);
    const int pi1 = (tb + 16) * 16 + (lane & 15);
    const float* arow0 = pr + ((size_t)(i0 + (pi0 >> 5)) * LL + j0 + (pi0 & 31)) * DPAIR
                         + (lane >> 4) * 8;
    const float* arow1 = pr + ((size_t)(i0 + (pi1 >> 5)) * LL + j0 + (pi1 & 31)) * DPAIR
                         + (lane >> 4) * 8;
    f32x4 c0 = (f32x4){0.f, 0.f, 0.f, 0.f};
    f32x4 c1 = (f32x4){0.f, 0.f, 0.f, 0.f};
    #pragma unroll
    for (int s = 0; s < 4; ++s) {
      const float4 u0 = *(const float4*)(arow0 + s * 32);
      const float4 u1 = *(const float4*)(arow0 + s * 32 + 4);
      const float4 v0 = *(const float4*)(arow1 + s * 32);
      const float4 v1 = *(const float4*)(arow1 + s * 32 + 4);
      bf16x8 a0, a1;
      a0[0] = (short)f2bf(u0.x); a0[1] = (short)f2bf(u0.y);
      a0[2] = (short)f2bf(u0.z); a0[3] = (short)f2bf(u0.w);
      a0[4] = (short)f2bf(u1.x); a0[5] = (short)f2bf(u1.y);
      a0[6] = (short)f2bf(u1.z); a0[7] = (short)f2bf(u1.w);
      a1[0] = (short)f2bf(v0.x); a1[1] = (short)f2bf(v0.y);
      a1[2] = (short)f2bf(v0.z); a1[3] = (short)f2bf(v0.w);
      a1[4] = (short)f2bf(v1.x); a1[5] = (short)f2bf(v1.y);
      a1[6] = (short)f2bf(v1.z); a1[7] = (short)f2bf(v1.w);
      c0 = __builtin_amdgcn_mfma_f32_16x16x32_bf16(a0, bfrag[s], c0, 0, 0, 0);
      c1 = __builtin_amdgcn_mfma_f32_16x16x32_bf16(a1, bfrag[s], c1, 0, 0, 0);
    }
    const int hcol = lane & 15;
    if (hcol < HH) {
      #pragma unroll
      for (int q = 0; q < 4; ++q) {
        ltile[(tb * 16 + (lane >> 4) * 4 + q) * 13 + hcol] = c0[q];
        ltile[((tb + 16) * 16 + (lane >> 4) * 4 + q) * 13 + hcol] = c1[q];
      }
    }
  }
  __syncthreads();

  // qk-extended GEMM + assemble + exp -> pb (bf16), p back into ltile
  for (int task = wv; task < 24; task += 8) {
    const int h = task >> 1, jb2 = task & 1;
    const bf16x8 a = *(const bf16x8*)&qth[(size_t)(h * LL + i0 + (lane & 15)) * 32
                                          + (lane >> 4) * 8];
    const bf16x8 b = *(const bf16x8*)&kth[(size_t)(h * LL + j0 + jb2 * 16 + (lane & 15)) * 32
                                          + (lane >> 4) * 8];
    f32x4 c = (f32x4){0.f, 0.f, 0.f, 0.f};
    c = __builtin_amdgcn_mfma_f32_16x16x32_bf16(a, b, c, 0, 0, 0);
    const int j = jb2 * 16 + (lane & 15);
    #pragma unroll
    for (int q = 0; q < 4; ++q) {
      const int ii = (lane >> 4) * 4 + q;
      const float bias = ltile[(ii * 32 + j) * 13 + h];
      const float l = c[q] + PAIR_SCALE * (bias + bpl[h]);
      const float p = __expf(l);
      pb[(size_t)(i0 + ii) * 6144 + h * 512 + j0 + j] = f2bf(p);
      ltile[(ii * 32 + j) * 13 + h] = p;   // same thread re-writes its own slot
    }
  }
  __syncthreads();

  // Z partials: owner thread per (ii,h), deterministic
  if (tid < 192) {
    const int ii = tid / 12, h = tid % 12;
    float s = 0.f;
    for (int j = 0; j < 32; ++j) s += ltile[(ii * 32 + j) * 13 + h];
    Zp[((size_t)jb * LL + i0 + ii) * 12 + h] = s;
  }
}

// -------- Kernel 3: merged PV + SV (independent halves, one dispatch) -------
// blocks 0..511   : res_pair PV for i = bid (8 waves = 8 d-tiles of 16)
// blocks 512..655 : res_s/res_p SV, b = bid-512: cb = b%36, it = b/36 (128 i rows)
__global__ __launch_bounds__(512) void k_pvsv(
    const float* __restrict__ pr, const unsigned short* __restrict__ pb,
    const float* __restrict__ Zp, const unsigned short* __restrict__ vsT,
    const unsigned short* __restrict__ vpT, const float* __restrict__ rot,
    const float* __restrict__ trans, unsigned short* __restrict__ resultsb)
{
  __shared__ __align__(16) unsigned short attn_lds[16 * 544];
  __shared__ float zz[12];
  __shared__ float cl[8][16][16];
  __shared__ float zs[128];
  const int tid = threadIdx.x;
  const int wv = tid >> 6, lane = tid & 63;

  if (blockIdx.x < 512) {
    // ---------------- PV half ----------------
    const int i = blockIdx.x;
    const uint4* src = (const uint4*)(pb + (size_t)i * 6144);
    for (int t = tid; t < 768; t += 512) {
      const int h = t >> 6, c8 = t & 63;
      *(uint4*)&attn_lds[h * 544 + c8 * 8] = src[t];
    }
    for (int t = tid; t < 272; t += 512)
      *(uint4*)&attn_lds[12 * 544 + t * 8] = (uint4){0, 0, 0, 0};
    if (tid < 12) {
      float s = 0.f;
      #pragma unroll
      for (int jb = 0; jb < 16; ++jb) s += Zp[((size_t)jb * LL + i) * 12 + tid];
      zz[tid] = 1.f / s;
    }
    __syncthreads();

    const int d0 = wv * 16;
    const int dl = lane & 15;
    const int kg = lane >> 4;
    const float* __restrict__ base = pr + (size_t)i * (LL * DPAIR) + d0 + dl;

    f32x4 c = (f32x4){0.f, 0.f, 0.f, 0.f};
    for (int ks = 0; ks < 16; ks += 2) {
      const int j0a = ks * 32 + kg * 8;
      const int j0b = j0a + 32;
      float ra[8], rb[8];
      #pragma unroll
      for (int e = 0; e < 8; ++e) ra[e] = base[(size_t)(j0a + e) * DPAIR];
      #pragma unroll
      for (int e = 0; e < 8; ++e) rb[e] = base[(size_t)(j0b + e) * DPAIR];
      bf16x8 a0, a1;
      #pragma unroll
      for (int e = 0; e < 8; ++e) { a0[e] = (short)f2bf(ra[e]); a1[e] = (short)f2bf(rb[e]); }
      const bf16x8 b0 = *(const bf16x8*)&attn_lds[(lane & 15) * 544 + ks * 32 + kg * 8];
      const bf16x8 b1 = *(const bf16x8*)&attn_lds[(lane & 15) * 544 + (ks + 1) * 32 + kg * 8];
      c = __builtin_amdgcn_mfma_f32_16x16x32_bf16(a0, b0, c, 0, 0, 0);
      c = __builtin_amdgcn_mfma_f32_16x16x32_bf16(a1, b1, c, 0, 0, 0);
    }
    const int h = lane & 15;
    if (h < HH) {
      const float zv = zz[h];
      #pragma unroll
      for (int q = 0; q < 4; ++q) {
        const int d = d0 + (lane >> 4) * 4 + q;
        resultsb[(size_t)i * RK + 576 + h * 128 + d] = f2bf(c[q] * zv);
      }
    }
    return;
  }

  // ---------------- SV half ----------------
  const int b = blockIdx.x - 512;
  const int cb = b % 36;
  const int it = b / 36;                      // 4 i-tiles of 128
  int h, rowbase, isvp = 0, halfb = 0;
  if (cb < 12) { h = cb; rowbase = h * 16; }
  else { const int v = cb - 12; h = v >> 1; halfb = v & 1; isvp = 1;
         rowbase = h * 24 + halfb * 8; }
  const unsigned short* __restrict__ vT = isvp ? vpT : vsT;
  const int ibase = it * 128 + wv * 16;

  // cooperative 1/Z for this block's 128 rows at head h
  if (tid < 128) {
    const int ii = it * 128 + tid;
    float s = 0.f;
    #pragma unroll
    for (int jb = 0; jb < 16; ++jb) s += Zp[((size_t)jb * LL + ii) * 12 + h];
    zs[tid] = 1.f / s;
  }
  __syncthreads();

  f32x4 c = (f32x4){0.f, 0.f, 0.f, 0.f};
  for (int ks = 0; ks < 16; ++ks) {
    const bf16x8 a = *(const bf16x8*)&pb[(size_t)(ibase + (lane & 15)) * 6144
                                         + h * 512 + ks * 32 + (lane >> 4) * 8];
    const bf16x8 bfr = *(const bf16x8*)&vT[(size_t)(rowbase + (lane & 15)) * LL
                                           + ks * 32 + (lane >> 4) * 8];
    c = __builtin_amdgcn_mfma_f32_16x16x32_bf16(a, bfr, c, 0, 0, 0);
  }
  if (!isvp) {
    #pragma unroll
    for (int r = 0; r < 4; ++r) {
      const int ii = ibase + (lane >> 4) * 4 + r;
      resultsb[(size_t)ii * RK + h * 16 + (lane & 15)] =
          f2bf(c[r] * zs[ii - it * 128]);
    }
  } else {
    #pragma unroll
    for (int r = 0; r < 4; ++r) {
      const int ii = ibase + (lane >> 4) * 4 + r;
      cl[wv][(lane >> 4) * 4 + r][lane & 15] = c[r] * zs[ii - it * 128];
    }
    __syncthreads();
    const int np = halfb ? 3 : 5;
    for (int t = tid; t < 128 * np; t += 512) {
      const int il = t / np, pl = t % np;
      const int p = halfb ? 5 + pl : pl;
      const int lc = p * 3 - (halfb ? 8 : 0);
      const int ii = it * 128 + il;
      const float a0 = cl[il >> 4][il & 15][lc + 0] - trans[ii * 3 + 0];
      const float a1 = cl[il >> 4][il & 15][lc + 1] - trans[ii * 3 + 1];
      const float a2 = cl[il >> 4][il & 15][lc + 2] - trans[ii * 3 + 2];
      const float* R = rot + ii * 9;
      const float o0 = a0 * R[0] + a1 * R[1] + a2 * R[2];
      const float o1 = a0 * R[3] + a1 * R[4] + a2 * R[5];
      const float o2 = a0 * R[6] + a1 * R[7] + a2 * R[8];
      unsigned short* rr = resultsb + (size_t)ii * RK;
      rr[192 + h * 24 + p * 3 + 0] = f2bf(o0);
      rr[192 + h * 24 + p * 3 + 1] = f2bf(o1);
      rr[192 + h * 24 + p * 3 + 2] = f2bf(o2);
      rr[480 + h * 8 + p] = f2bf(sqrtf(o0 * o0 + o1 * o1 + o2 * o2 + 1e-8f));
    }
  }
}

// ---------------- Kernel 5a: output GEMM via MFMA, K-split ------------------
__global__ __launch_bounds__(256) void k_outg(
    const unsigned short* __restrict__ resb, const unsigned short* __restrict__ WoT,
    float* __restrict__ partial)
{
  const int i0 = blockIdx.x * 64;
  const int c0 = blockIdx.y * 32;
  const int k0 = blockIdx.z * 544;
  const int wv = threadIdx.x >> 6, lane = threadIdx.x & 63;
  const int aRow = i0 + wv * 16 + (lane & 15);

  f32x4 acc0 = (f32x4){0.f, 0.f, 0.f, 0.f};
  f32x4 acc1 = (f32x4){0.f, 0.f, 0.f, 0.f};
  for (int ks = 0; ks < 17; ++ks) {
    const int kk = k0 + ks * 32 + (lane >> 4) * 8;
    const bf16x8 a = *(const bf16x8*)&resb[(size_t)aRow * RK + kk];
    const bf16x8 b0 = *(const bf16x8*)&WoT[(size_t)(c0 + (lane & 15)) * RK + kk];
    const bf16x8 b1 = *(const bf16x8*)&WoT[(size_t)(c0 + 16 + (lane & 15)) * RK + kk];
    acc0 = __builtin_amdgcn_mfma_f32_16x16x32_bf16(a, b0, acc0, 0, 0, 0);
    acc1 = __builtin_amdgcn_mfma_f32_16x16x32_bf16(a, b1, acc1, 0, 0, 0);
  }
  float* pbase = partial + (size_t)blockIdx.z * (LL * 384);
  #pragma unroll
  for (int r = 0; r < 4; ++r) {
    const int ii = i0 + wv * 16 + (lane >> 4) * 4 + r;
    float* prow = pbase + (size_t)ii * 384 + c0 + (lane & 15);
    prow[0]  = acc0[r];
    prow[16] = acc1[r];
  }
}

// ---------------- Kernel 5b: reduce partials + bias -------------------------
__global__ __launch_bounds__(256) void k_out2(
    const float* __restrict__ partial, const float* __restrict__ bout,
    float* __restrict__ out)
{
  const int e = blockIdx.x * 256 + threadIdx.x;
  const int c = e % 384;
  out[e] = bout[c] + partial[e] + partial[e + LL * 384]
         + partial[e + 2 * LL * 384] + partial[e + 3 * LL * 384];
}

extern "C" void kernel_launch(void* const* d_in, const int* in_sizes, int n_in,
                              void* d_out, int out_size, void* d_ws, size_t ws_size,
                              hipStream_t stream)
{
  const float* x     = (const float*)d_in[0];
  const float* prw   = (const float*)d_in[1];
  const float* rot   = (const float*)d_in[2];
  const float* trans = (const float*)d_in[3];
  const float* Ws    = (const float*)d_in[4];
  const float* Wp    = (const float*)d_in[5];
  const float* pw    = (const float*)d_in[6];
  const float* Wpair = (const float*)d_in[7];
  const float* bpair = (const float*)d_in[8];
  const float* Wout  = (const float*)d_in[9];
  const float* bout  = (const float*)d_in[10];

  float* ws = (float*)d_ws;
  unsigned short* qth = (unsigned short*)ws;                // 98304 f
  unsigned short* kth = (unsigned short*)(ws + 98304);      // 98304 f
  unsigned short* vsT = (unsigned short*)(ws + 196608);     // 49152 f
  unsigned short* vpT = (unsigned short*)(ws + 245760);     // 73728 f
  unsigned short* pb  = (unsigned short*)(ws + 319488);     // 1572864 f
  float* Zp      = ws + 1892352;                            // 98304 f
  unsigned short* resultsb = (unsigned short*)(ws + 1996800); // 557056 f
  unsigned short* WoT = (unsigned short*)(ws + 2553856);    // 417792 f
  float* partial = ws + 2971648;                            // 786432 f
  unsigned short* xb = (unsigned short*)(ws + 3758080);     // 98304 f
  unsigned short* WcatT = (unsigned short*)(ws + 3856384);  // 221184 f
  float* rawq    = ws + 4077568;                            // 589824 f (ends 4667392)
  float* out     = (float*)d_out;

  k_preps<<<402, 256, 0, stream>>>(x, Ws, Wp, Wout, xb, WcatT, WoT, resultsb);
  k_qkv_gemm<<<dim3(8, 72), 256, 0, stream>>>(xb, WcatT, rawq);
  k_post<<<128, 256, 0, stream>>>(rawq, rot, trans, pw, qth, kth, vsT, vpT);
  k_logits<<<512, 512, 0, stream>>>(prw, Wpair, bpair, qth, kth, pb, Zp);
  k_pvsv<<<656, 512, 0, stream>>>(prw, pb, Zp, vsT, vpT, rot, trans, resultsb);
  k_outg<<<dim3(8, 12, 4), 256, 0, stream>>>(resultsb, WoT, partial);
  k_out2<<<768, 256, 0, stream>>>(partial, bout, out);
}